// Round 1
// baseline (804.401 us; speedup 1.0000x reference)
//
#include <hip/hip_runtime.h>
#include <hip/hip_bf16.h>

typedef float f32x4 __attribute__((ext_vector_type(4)));
typedef __bf16 bf16x8 __attribute__((ext_vector_type(8)));
typedef unsigned short us8 __attribute__((ext_vector_type(8)));

#define MBYTE (1ull << 20)

__device__ __forceinline__ unsigned short f2bf(float f) {
    unsigned int u = __float_as_uint(f);
    u += 0x7fffu + ((u >> 16) & 1u);
    return (unsigned short)(u >> 16);
}

__device__ __forceinline__ f32x4 mfma16(bf16x8 a, bf16x8 b, f32x4 c) {
    return __builtin_amdgcn_mfma_f32_16x16x32_bf16(a, b, c, 0, 0, 0);
}

// ---------------- LayerNorm: fp32 [rows][1024] -> bf16 ----------------
__global__ __launch_bounds__(256) void ln_kernel(const float* __restrict__ x,
                                                 unsigned short* __restrict__ out) {
    int row = blockIdx.x;
    int t = threadIdx.x;
    const float* xr = x + (size_t)row * 1024;
    float4 v = *(const float4*)(xr + t * 4);
    float s = v.x + v.y + v.z + v.w;
    float ss = v.x * v.x + v.y * v.y + v.z * v.z + v.w * v.w;
    #pragma unroll
    for (int off = 1; off < 64; off <<= 1) {
        s += __shfl_xor(s, off);
        ss += __shfl_xor(ss, off);
    }
    __shared__ float ps[4], pss[4];
    int wid = t >> 6, lane = t & 63;
    if (lane == 0) { ps[wid] = s; pss[wid] = ss; }
    __syncthreads();
    s = ps[0] + ps[1] + ps[2] + ps[3];
    ss = pss[0] + pss[1] + pss[2] + pss[3];
    float mean = s * (1.0f / 1024.0f);
    float var = ss * (1.0f / 1024.0f) - mean * mean;
    float rs = rsqrtf(var + 1e-6f);
    ushort4 ov;
    ov.x = f2bf((v.x - mean) * rs);
    ov.y = f2bf((v.y - mean) * rs);
    ov.z = f2bf((v.z - mean) * rs);
    ov.w = f2bf((v.w - mean) * rs);
    *(ushort4*)(out + (size_t)row * 1024 + t * 4) = ov;
}

// ------------- transpose + fp32->bf16: W[K][N] -> Wt[N][K] -------------
__global__ __launch_bounds__(256) void convT_kernel(const float* __restrict__ W,
                                                    unsigned short* __restrict__ Wt,
                                                    int K, int N) {
    __shared__ float tile[32][33];
    int t = threadIdx.x;
    int tx = t & 31, ty = t >> 5;  // ty 0..7
    int bx = blockIdx.x, by = blockIdx.y;
    #pragma unroll
    for (int r = 0; r < 4; r++) {
        int row = by * 32 + ty + r * 8;
        int col = bx * 32 + tx;
        tile[ty + r * 8][tx] = W[(size_t)row * N + col];
    }
    __syncthreads();
    #pragma unroll
    for (int r = 0; r < 4; r++) {
        int orow = bx * 32 + ty + r * 8;  // n
        int ocol = by * 32 + tx;          // k
        Wt[(size_t)orow * K + ocol] = f2bf(tile[tx][ty + r * 8]);
    }
}

// ---------------- GEMM: C[M][N] = A[M][K](bf16) @ Bt[N][K]^T ----------------
// EPI 0: outB = bf16(C + bias)
// EPI 1: outB = bf16(gelu_tanh(C + bias))
// EPI 2: outF = C + bias + res
template <int EPI>
__global__ __launch_bounds__(256) void gemm_bt(const unsigned short* __restrict__ A,
                                               const unsigned short* __restrict__ Bt,
                                               const float* __restrict__ bias,
                                               const float* __restrict__ res,
                                               float* __restrict__ outF,
                                               unsigned short* __restrict__ outB,
                                               int M, int N, int K) {
    __shared__ unsigned short As[128][40];
    __shared__ unsigned short Bs[128][40];
    int t = threadIdx.x;
    int lane = t & 63, wid = t >> 6;
    int bm = blockIdx.y, bn = blockIdx.x;
    int wm = wid >> 1, wn = wid & 1;
    f32x4 acc[4][4] = {};

    int srow = t >> 1, scol = (t & 1) * 16;
    const unsigned short* gA = A + (size_t)(bm * 128 + srow) * K + scol;
    const unsigned short* gB = Bt + (size_t)(bn * 128 + srow) * K + scol;

    for (int k0 = 0; k0 < K; k0 += 32) {
        __syncthreads();
        us8 a0 = *(const us8*)(gA + k0);
        us8 a1 = *(const us8*)(gA + k0 + 8);
        us8 b0 = *(const us8*)(gB + k0);
        us8 b1 = *(const us8*)(gB + k0 + 8);
        *(us8*)&As[srow][scol] = a0;
        *(us8*)&As[srow][scol + 8] = a1;
        *(us8*)&Bs[srow][scol] = b0;
        *(us8*)&Bs[srow][scol + 8] = b1;
        __syncthreads();
        bf16x8 af[4], bf[4];
        #pragma unroll
        for (int m = 0; m < 4; m++)
            af[m] = *(const bf16x8*)&As[wm * 64 + m * 16 + (lane & 15)][(lane >> 4) * 8];
        #pragma unroll
        for (int n = 0; n < 4; n++)
            bf[n] = *(const bf16x8*)&Bs[wn * 64 + n * 16 + (lane & 15)][(lane >> 4) * 8];
        #pragma unroll
        for (int m = 0; m < 4; m++)
            #pragma unroll
            for (int n = 0; n < 4; n++)
                acc[m][n] = mfma16(af[m], bf[n], acc[m][n]);
    }

    #pragma unroll
    for (int m = 0; m < 4; m++) {
        #pragma unroll
        for (int n = 0; n < 4; n++) {
            int col = bn * 128 + wn * 64 + n * 16 + (lane & 15);
            float bv = bias[col];
            #pragma unroll
            for (int r = 0; r < 4; r++) {
                int row = bm * 128 + wm * 64 + m * 16 + (lane >> 4) * 4 + r;
                float val = acc[m][n][r] + bv;
                if (EPI == 0) {
                    outB[(size_t)row * N + col] = f2bf(val);
                } else if (EPI == 1) {
                    float g = 0.5f * val *
                              (1.0f + tanhf(0.7978845608028654f *
                                            (val + 0.044715f * val * val * val)));
                    outB[(size_t)row * N + col] = f2bf(g);
                } else {
                    outF[(size_t)row * N + col] = val + res[(size_t)row * N + col];
                }
            }
        }
    }
}

// ---------------- Flash attention ----------------
// qkv bf16 [B*L][3*16*64] laid out (sel, head, d). o bf16 [B*L][1024].
// grid: (L/64) * (B*H) blocks of 256 threads; each wave owns 16 q rows.
__global__ __launch_bounds__(256) void attn_kernel(const unsigned short* __restrict__ qkv,
                                                   unsigned short* __restrict__ o) {
    int bid = blockIdx.x;
    int qb = bid & 31;       // q tile (64 rows)
    int bh = bid >> 5;
    int b = bh >> 4, h = bh & 15;
    int t = threadIdx.x, lane = t & 63, wid = t >> 6;

    const unsigned short* base = qkv + (size_t)b * 2048 * 3072 + h * 64;

    __shared__ unsigned short Ks[32][72];
    __shared__ unsigned short Vt[64][40];
    __shared__ unsigned short Pw[4][16][40];

    // Q fragments (held whole loop)
    bf16x8 aq[2];
    {
        int qrow = qb * 64 + wid * 16 + (lane & 15);
        const unsigned short* qp = base + (size_t)qrow * 3072 + (lane >> 4) * 8;
        aq[0] = *(const bf16x8*)(qp);
        aq[1] = *(const bf16x8*)(qp + 32);
    }

    float m_old[4], lsum[4];
    f32x4 accO[4] = {};
    #pragma unroll
    for (int r = 0; r < 4; r++) { m_old[r] = -1e30f; lsum[r] = 0.0f; }

    int key_t = t >> 3;          // 0..31
    int d0_t = (t & 7) * 8;      // 0..56

    for (int kt = 0; kt < 64; kt++) {
        __syncthreads();
        const unsigned short* kp = base + 1024 + (size_t)(kt * 32 + key_t) * 3072 + d0_t;
        const unsigned short* vp = base + 2048 + (size_t)(kt * 32 + key_t) * 3072 + d0_t;
        us8 kv = *(const us8*)kp;
        us8 vv = *(const us8*)vp;
        *(us8*)&Ks[key_t][d0_t] = kv;
        #pragma unroll
        for (int j = 0; j < 8; j++) Vt[d0_t + j][key_t] = vv[j];
        __syncthreads();

        // S = Q @ K^T  (two 16-key fragments, K-dim 64 = 2 mfma each)
        f32x4 s[2] = {};
        #pragma unroll
        for (int n = 0; n < 2; n++) {
            #pragma unroll
            for (int c = 0; c < 2; c++) {
                bf16x8 bk = *(const bf16x8*)&Ks[n * 16 + (lane & 15)][c * 32 + (lane >> 4) * 8];
                s[n] = mfma16(aq[c], bk, s[n]);
            }
        }

        // online softmax (rows = (lane>>4)*4 + r, cols across 16-lane groups)
        float corr[4];
        #pragma unroll
        for (int r = 0; r < 4; r++) {
            float v0 = s[0][r] * 0.125f;
            float v1 = s[1][r] * 0.125f;
            float mx = fmaxf(v0, v1);
            #pragma unroll
            for (int off = 1; off < 16; off <<= 1) mx = fmaxf(mx, __shfl_xor(mx, off));
            float mnew = fmaxf(m_old[r], mx);
            corr[r] = __expf(m_old[r] - mnew);
            float p0 = __expf(v0 - mnew);
            float p1 = __expf(v1 - mnew);
            s[0][r] = p0;
            s[1][r] = p1;
            float rs = p0 + p1;
            #pragma unroll
            for (int off = 1; off < 16; off <<= 1) rs += __shfl_xor(rs, off);
            lsum[r] = lsum[r] * corr[r] + rs;
            m_old[r] = mnew;
        }
        #pragma unroll
        for (int nn = 0; nn < 4; nn++)
            #pragma unroll
            for (int r = 0; r < 4; r++) accO[nn][r] *= corr[r];

        // P -> LDS (per-wave), then consume as MFMA A operand
        #pragma unroll
        for (int nf = 0; nf < 2; nf++)
            #pragma unroll
            for (int r = 0; r < 4; r++)
                Pw[wid][(lane >> 4) * 4 + r][nf * 16 + (lane & 15)] = f2bf(s[nf][r]);

        bf16x8 pa = *(const bf16x8*)&Pw[wid][lane & 15][(lane >> 4) * 8];
        #pragma unroll
        for (int nn = 0; nn < 4; nn++) {
            bf16x8 bv = *(const bf16x8*)&Vt[nn * 16 + (lane & 15)][(lane >> 4) * 8];
            accO[nn] = mfma16(pa, bv, accO[nn]);
        }
    }

    // epilogue: O / lsum -> bf16 out [B*L][1024]
    #pragma unroll
    for (int nn = 0; nn < 4; nn++) {
        int col = h * 64 + nn * 16 + (lane & 15);
        #pragma unroll
        for (int r = 0; r < 4; r++) {
            int row = qb * 64 + wid * 16 + (lane >> 4) * 4 + r;
            float val = accO[nn][r] / lsum[r];
            o[(size_t)(b * 2048 + row) * 1024 + col] = f2bf(val);
        }
    }
}

extern "C" void kernel_launch(void* const* d_in, const int* in_sizes, int n_in,
                              void* d_out, int out_size, void* d_ws, size_t ws_size,
                              hipStream_t stream) {
    const float* x      = (const float*)d_in[0];
    const float* qkv_w  = (const float*)d_in[1];
    const float* qkv_b  = (const float*)d_in[2];
    const float* proj_w = (const float*)d_in[3];
    const float* proj_b = (const float*)d_in[4];
    const float* fc1_w  = (const float*)d_in[5];
    const float* fc1_b  = (const float*)d_in[6];
    const float* fc2_w  = (const float*)d_in[7];
    const float* fc2_b  = (const float*)d_in[8];
    float* out = (float*)d_out;

    char* ws = (char*)d_ws;
    unsigned short* h_buf   = (unsigned short*)(ws + 0 * MBYTE);    // 16 MB (reused for h2)
    unsigned short* qkv_buf = (unsigned short*)(ws + 16 * MBYTE);   // 48 MB
    unsigned short* o_buf   = (unsigned short*)(ws + 64 * MBYTE);   // 16 MB
    float*          x2_buf  = (float*)(ws + 80 * MBYTE);            // 32 MB
    unsigned short* wqT     = (unsigned short*)(ws + 112 * MBYTE);  // 6 MB
    unsigned short* wpT     = (unsigned short*)(ws + 118 * MBYTE);  // 2 MB
    unsigned short* w1T     = (unsigned short*)(ws + 120 * MBYTE);  // 8 MB
    unsigned short* w2T     = (unsigned short*)(ws + 128 * MBYTE);  // 8 MB
    unsigned short* g_buf   = (unsigned short*)(ws + 16 * MBYTE);   // 64 MB (reuse qkv+o)

    const int M = 8192;  // B*L

    // weight conversion (transpose to [N][K] bf16)
    convT_kernel<<<dim3(3072 / 32, 1024 / 32), 256, 0, stream>>>(qkv_w, wqT, 1024, 3072);
    convT_kernel<<<dim3(1024 / 32, 1024 / 32), 256, 0, stream>>>(proj_w, wpT, 1024, 1024);
    convT_kernel<<<dim3(4096 / 32, 1024 / 32), 256, 0, stream>>>(fc1_w, w1T, 1024, 4096);
    convT_kernel<<<dim3(1024 / 32, 4096 / 32), 256, 0, stream>>>(fc2_w, w2T, 4096, 1024);

    // LN1
    ln_kernel<<<M, 256, 0, stream>>>(x, h_buf);

    // qkv = h @ qkv_w + b  -> bf16
    gemm_bt<0><<<dim3(3072 / 128, M / 128), 256, 0, stream>>>(
        h_buf, wqT, qkv_b, nullptr, nullptr, qkv_buf, M, 3072, 1024);

    // attention
    attn_kernel<<<dim3(32 * 64), 256, 0, stream>>>(qkv_buf, o_buf);

    // x2 = x + o @ proj_w + b
    gemm_bt<2><<<dim3(1024 / 128, M / 128), 256, 0, stream>>>(
        o_buf, wpT, proj_b, x, x2_buf, nullptr, M, 1024, 1024);

    // LN2
    ln_kernel<<<M, 256, 0, stream>>>(x2_buf, h_buf);

    // g = gelu(h2 @ fc1_w + b) -> bf16
    gemm_bt<1><<<dim3(4096 / 128, M / 128), 256, 0, stream>>>(
        h_buf, w1T, fc1_b, nullptr, nullptr, g_buf, M, 4096, 1024);

    // out = x2 + g @ fc2_w + b
    gemm_bt<2><<<dim3(1024 / 128, M / 128), 256, 0, stream>>>(
        g_buf, w2T, fc2_b, x2_buf, out, nullptr, M, 1024, 4096);
}

// Round 2
// 629.753 us; speedup vs baseline: 1.2773x; 1.2773x over previous
//
#include <hip/hip_runtime.h>
#include <hip/hip_bf16.h>

typedef float f32x4 __attribute__((ext_vector_type(4)));
typedef __bf16 bf16x8 __attribute__((ext_vector_type(8)));
typedef unsigned short us8 __attribute__((ext_vector_type(8)));

#define MBYTE (1ull << 20)

__device__ __forceinline__ unsigned short f2bf(float f) {
    unsigned int u = __float_as_uint(f);
    u += 0x7fffu + ((u >> 16) & 1u);
    return (unsigned short)(u >> 16);
}

__device__ __forceinline__ f32x4 mfma16(bf16x8 a, bf16x8 b, f32x4 c) {
    return __builtin_amdgcn_mfma_f32_16x16x32_bf16(a, b, c, 0, 0, 0);
}

// ---------------- LayerNorm: fp32 [rows][1024] -> bf16 ----------------
__global__ __launch_bounds__(256) void ln_kernel(const float* __restrict__ x,
                                                 unsigned short* __restrict__ out) {
    int row = blockIdx.x;
    int t = threadIdx.x;
    const float* xr = x + (size_t)row * 1024;
    float4 v = *(const float4*)(xr + t * 4);
    float s = v.x + v.y + v.z + v.w;
    float ss = v.x * v.x + v.y * v.y + v.z * v.z + v.w * v.w;
    #pragma unroll
    for (int off = 1; off < 64; off <<= 1) {
        s += __shfl_xor(s, off);
        ss += __shfl_xor(ss, off);
    }
    __shared__ float ps[4], pss[4];
    int wid = t >> 6, lane = t & 63;
    if (lane == 0) { ps[wid] = s; pss[wid] = ss; }
    __syncthreads();
    s = ps[0] + ps[1] + ps[2] + ps[3];
    ss = pss[0] + pss[1] + pss[2] + pss[3];
    float mean = s * (1.0f / 1024.0f);
    float var = ss * (1.0f / 1024.0f) - mean * mean;
    float rs = rsqrtf(var + 1e-6f);
    ushort4 ov;
    ov.x = f2bf((v.x - mean) * rs);
    ov.y = f2bf((v.y - mean) * rs);
    ov.z = f2bf((v.z - mean) * rs);
    ov.w = f2bf((v.w - mean) * rs);
    *(ushort4*)(out + (size_t)row * 1024 + t * 4) = ov;
}

// ------------- transpose + fp32->bf16: W[K][N] -> Wt[N][K] -------------
__global__ __launch_bounds__(256) void convT_kernel(const float* __restrict__ W,
                                                    unsigned short* __restrict__ Wt,
                                                    int K, int N) {
    __shared__ float tile[32][33];
    int t = threadIdx.x;
    int tx = t & 31, ty = t >> 5;  // ty 0..7
    int bx = blockIdx.x, by = blockIdx.y;
    #pragma unroll
    for (int r = 0; r < 4; r++) {
        int row = by * 32 + ty + r * 8;
        int col = bx * 32 + tx;
        tile[ty + r * 8][tx] = W[(size_t)row * N + col];
    }
    __syncthreads();
    #pragma unroll
    for (int r = 0; r < 4; r++) {
        int orow = bx * 32 + ty + r * 8;  // n
        int ocol = by * 32 + tx;          // k
        Wt[(size_t)orow * K + ocol] = f2bf(tile[tx][ty + r * 8]);
    }
}

// ------------- V transpose: qkv V-part bf16 -> vT[bh][64][2048] -------------
__global__ __launch_bounds__(256) void vT_kernel(const unsigned short* __restrict__ qkv,
                                                 unsigned short* __restrict__ vT) {
    __shared__ unsigned short tile[32][34];
    int t = threadIdx.x;
    int tx = t & 31, ty = t >> 5;  // ty 0..7
    int lt = blockIdx.x, dt = blockIdx.y, bh = blockIdx.z;
    int b = bh >> 4, h = bh & 15;
    const unsigned short* src = qkv + (size_t)(b * 2048 + lt * 32) * 3072 + 2048 + h * 64 + dt * 32;
    #pragma unroll
    for (int r = 0; r < 4; r++)
        tile[ty + r * 8][tx] = src[(size_t)(ty + r * 8) * 3072 + tx];
    __syncthreads();
    unsigned short* dst = vT + ((size_t)bh * 64 + dt * 32) * 2048 + (size_t)lt * 32;
    #pragma unroll
    for (int r = 0; r < 4; r++)
        dst[(size_t)(ty + r * 8) * 2048 + tx] = tile[tx][ty + r * 8];
}

// ---------------- GEMM: C[M][N] = A[M][K](bf16) @ Bt[N][K]^T ----------------
template <int EPI>
__global__ __launch_bounds__(256) void gemm_bt(const unsigned short* __restrict__ A,
                                               const unsigned short* __restrict__ Bt,
                                               const float* __restrict__ bias,
                                               const float* __restrict__ res,
                                               float* __restrict__ outF,
                                               unsigned short* __restrict__ outB,
                                               int M, int N, int K) {
    __shared__ unsigned short As[128][40];
    __shared__ unsigned short Bs[128][40];
    int t = threadIdx.x;
    int lane = t & 63, wid = t >> 6;
    int bm = blockIdx.y, bn = blockIdx.x;
    int wm = wid >> 1, wn = wid & 1;
    f32x4 acc[4][4] = {};

    int srow = t >> 1, scol = (t & 1) * 16;
    const unsigned short* gA = A + (size_t)(bm * 128 + srow) * K + scol;
    const unsigned short* gB = Bt + (size_t)(bn * 128 + srow) * K + scol;

    for (int k0 = 0; k0 < K; k0 += 32) {
        __syncthreads();
        us8 a0 = *(const us8*)(gA + k0);
        us8 a1 = *(const us8*)(gA + k0 + 8);
        us8 b0 = *(const us8*)(gB + k0);
        us8 b1 = *(const us8*)(gB + k0 + 8);
        *(us8*)&As[srow][scol] = a0;
        *(us8*)&As[srow][scol + 8] = a1;
        *(us8*)&Bs[srow][scol] = b0;
        *(us8*)&Bs[srow][scol + 8] = b1;
        __syncthreads();
        bf16x8 af[4], bf[4];
        #pragma unroll
        for (int m = 0; m < 4; m++)
            af[m] = *(const bf16x8*)&As[wm * 64 + m * 16 + (lane & 15)][(lane >> 4) * 8];
        #pragma unroll
        for (int n = 0; n < 4; n++)
            bf[n] = *(const bf16x8*)&Bs[wn * 64 + n * 16 + (lane & 15)][(lane >> 4) * 8];
        #pragma unroll
        for (int m = 0; m < 4; m++)
            #pragma unroll
            for (int n = 0; n < 4; n++)
                acc[m][n] = mfma16(af[m], bf[n], acc[m][n]);
    }

    #pragma unroll
    for (int m = 0; m < 4; m++) {
        #pragma unroll
        for (int n = 0; n < 4; n++) {
            int col = bn * 128 + wn * 64 + n * 16 + (lane & 15);
            float bv = bias[col];
            #pragma unroll
            for (int r = 0; r < 4; r++) {
                int row = bm * 128 + wm * 64 + m * 16 + (lane >> 4) * 4 + r;
                float val = acc[m][n][r] + bv;
                if (EPI == 0) {
                    outB[(size_t)row * N + col] = f2bf(val);
                } else if (EPI == 1) {
                    float g = 0.5f * val *
                              (1.0f + tanhf(0.7978845608028654f *
                                            (val + 0.044715f * val * val * val)));
                    outB[(size_t)row * N + col] = f2bf(g);
                } else {
                    outF[(size_t)row * N + col] = val + res[(size_t)row * N + col];
                }
            }
        }
    }
}

// ---------------- Flash attention v2 ----------------
// qkv bf16 [B*L][3*16*64]; vT bf16 [bh][64][2048]; o bf16 [B*L][1024].
// grid: 32 qtiles * 64 bh; 256 threads; wave owns 16 q rows; KVBLK=64.
__global__ __launch_bounds__(256) void attn_kernel(const unsigned short* __restrict__ qkv,
                                                   const unsigned short* __restrict__ vT,
                                                   unsigned short* __restrict__ o) {
    int bid = blockIdx.x;
    int qb = bid & 31;       // q tile (64 rows)
    int bh = bid >> 5;
    int b = bh >> 4, h = bh & 15;
    int t = threadIdx.x, lane = t & 63, wid = t >> 6;

    const unsigned short* base = qkv + (size_t)b * 2048 * 3072 + h * 64;
    const unsigned short* vbase = vT + (size_t)bh * 64 * 2048;

    __shared__ unsigned short Ks[64][72];       // [key][d]
    __shared__ unsigned short Vs[64][72];       // [d][key]
    __shared__ unsigned short Pw[4][16][72];    // per-wave P [q][key]

    // Q fragments (held whole loop)
    bf16x8 aq[2];
    {
        int qrow = qb * 64 + wid * 16 + (lane & 15);
        const unsigned short* qp = base + (size_t)qrow * 3072 + (lane >> 4) * 8;
        aq[0] = *(const bf16x8*)(qp);
        aq[1] = *(const bf16x8*)(qp + 32);
    }

    float m_old[4], lsum[4];
    f32x4 accO[4] = {};
    #pragma unroll
    for (int r = 0; r < 4; r++) { m_old[r] = -1e30f; lsum[r] = 0.0f; }

    int srow = t >> 2;          // 0..63
    int scol = (t & 3) * 16;    // 0..48

    for (int kt = 0; kt < 32; kt++) {
        __syncthreads();
        const unsigned short* kp = base + 1024 + (size_t)(kt * 64 + srow) * 3072 + scol;
        const unsigned short* vp = vbase + (size_t)srow * 2048 + kt * 64 + scol;
        us8 k0 = *(const us8*)kp;
        us8 k1 = *(const us8*)(kp + 8);
        us8 v0 = *(const us8*)vp;
        us8 v1 = *(const us8*)(vp + 8);
        *(us8*)&Ks[srow][scol] = k0;
        *(us8*)&Ks[srow][scol + 8] = k1;
        *(us8*)&Vs[srow][scol] = v0;
        *(us8*)&Vs[srow][scol + 8] = v1;
        __syncthreads();

        // S = Q @ K^T : 4 key fragments of 16, d=64 (2 mfma each)
        f32x4 s[4] = {};
        #pragma unroll
        for (int nf = 0; nf < 4; nf++) {
            #pragma unroll
            for (int c = 0; c < 2; c++) {
                bf16x8 bk = *(const bf16x8*)&Ks[nf * 16 + (lane & 15)][c * 32 + (lane >> 4) * 8];
                s[nf] = mfma16(aq[c], bk, s[nf]);
            }
        }

        // online softmax (rows = (lane>>4)*4 + r, 64 keys = 4 frags x 16 lanes)
        float corr[4];
        #pragma unroll
        for (int r = 0; r < 4; r++) {
            float x0 = s[0][r] * 0.125f;
            float x1 = s[1][r] * 0.125f;
            float x2 = s[2][r] * 0.125f;
            float x3 = s[3][r] * 0.125f;
            float mx = fmaxf(fmaxf(x0, x1), fmaxf(x2, x3));
            #pragma unroll
            for (int off = 1; off < 16; off <<= 1) mx = fmaxf(mx, __shfl_xor(mx, off));
            float mnew = fmaxf(m_old[r], mx);
            corr[r] = __expf(m_old[r] - mnew);
            float p0 = __expf(x0 - mnew);
            float p1 = __expf(x1 - mnew);
            float p2 = __expf(x2 - mnew);
            float p3 = __expf(x3 - mnew);
            s[0][r] = p0; s[1][r] = p1; s[2][r] = p2; s[3][r] = p3;
            float rs = p0 + p1 + p2 + p3;
            #pragma unroll
            for (int off = 1; off < 16; off <<= 1) rs += __shfl_xor(rs, off);
            lsum[r] = lsum[r] * corr[r] + rs;
            m_old[r] = mnew;
        }
        #pragma unroll
        for (int nn = 0; nn < 4; nn++)
            #pragma unroll
            for (int r = 0; r < 4; r++) accO[nn][r] *= corr[r];

        // P -> LDS (per-wave)
        #pragma unroll
        for (int nf = 0; nf < 4; nf++)
            #pragma unroll
            for (int r = 0; r < 4; r++)
                Pw[wid][(lane >> 4) * 4 + r][nf * 16 + (lane & 15)] = f2bf(s[nf][r]);

        // PV: O[q][d] += P[q][k] * V[k][d], k=64 (2 kg blocks), d=64 (4 frags)
        #pragma unroll
        for (int kg = 0; kg < 2; kg++) {
            bf16x8 pa = *(const bf16x8*)&Pw[wid][lane & 15][kg * 32 + (lane >> 4) * 8];
            #pragma unroll
            for (int nn = 0; nn < 4; nn++) {
                bf16x8 bv = *(const bf16x8*)&Vs[nn * 16 + (lane & 15)][kg * 32 + (lane >> 4) * 8];
                accO[nn] = mfma16(pa, bv, accO[nn]);
            }
        }
    }

    // epilogue: O / lsum -> bf16 out [B*L][1024]
    #pragma unroll
    for (int nn = 0; nn < 4; nn++) {
        int col = h * 64 + nn * 16 + (lane & 15);
        #pragma unroll
        for (int r = 0; r < 4; r++) {
            int row = qb * 64 + wid * 16 + (lane >> 4) * 4 + r;
            float val = accO[nn][r] / lsum[r];
            o[(size_t)(b * 2048 + row) * 1024 + col] = f2bf(val);
        }
    }
}

extern "C" void kernel_launch(void* const* d_in, const int* in_sizes, int n_in,
                              void* d_out, int out_size, void* d_ws, size_t ws_size,
                              hipStream_t stream) {
    const float* x      = (const float*)d_in[0];
    const float* qkv_w  = (const float*)d_in[1];
    const float* qkv_b  = (const float*)d_in[2];
    const float* proj_w = (const float*)d_in[3];
    const float* proj_b = (const float*)d_in[4];
    const float* fc1_w  = (const float*)d_in[5];
    const float* fc1_b  = (const float*)d_in[6];
    const float* fc2_w  = (const float*)d_in[7];
    const float* fc2_b  = (const float*)d_in[8];
    float* out = (float*)d_out;

    char* ws = (char*)d_ws;
    unsigned short* h_buf   = (unsigned short*)(ws + 0 * MBYTE);    // 16 MB (reused for h2)
    unsigned short* qkv_buf = (unsigned short*)(ws + 16 * MBYTE);   // 48 MB
    unsigned short* o_buf   = (unsigned short*)(ws + 64 * MBYTE);   // 16 MB
    float*          x2_buf  = (float*)(ws + 80 * MBYTE);            // 32 MB
    unsigned short* vT_buf  = (unsigned short*)(ws + 80 * MBYTE);   // 17 MB (dead before x2 written)
    unsigned short* wqT     = (unsigned short*)(ws + 112 * MBYTE);  // 6 MB
    unsigned short* wpT     = (unsigned short*)(ws + 118 * MBYTE);  // 2 MB
    unsigned short* w1T     = (unsigned short*)(ws + 120 * MBYTE);  // 8 MB
    unsigned short* w2T     = (unsigned short*)(ws + 128 * MBYTE);  // 8 MB
    unsigned short* g_buf   = (unsigned short*)(ws + 16 * MBYTE);   // 64 MB (reuse qkv+o)

    const int M = 8192;  // B*L

    // weight conversion (transpose to [N][K] bf16)
    convT_kernel<<<dim3(3072 / 32, 1024 / 32), 256, 0, stream>>>(qkv_w, wqT, 1024, 3072);
    convT_kernel<<<dim3(1024 / 32, 1024 / 32), 256, 0, stream>>>(proj_w, wpT, 1024, 1024);
    convT_kernel<<<dim3(4096 / 32, 1024 / 32), 256, 0, stream>>>(fc1_w, w1T, 1024, 4096);
    convT_kernel<<<dim3(1024 / 32, 4096 / 32), 256, 0, stream>>>(fc2_w, w2T, 4096, 1024);

    // LN1
    ln_kernel<<<M, 256, 0, stream>>>(x, h_buf);

    // qkv = h @ qkv_w + b  -> bf16
    gemm_bt<0><<<dim3(3072 / 128, M / 128), 256, 0, stream>>>(
        h_buf, wqT, qkv_b, nullptr, nullptr, qkv_buf, M, 3072, 1024);

    // V transpose for attention
    vT_kernel<<<dim3(64, 2, 64), 256, 0, stream>>>(qkv_buf, vT_buf);

    // attention
    attn_kernel<<<dim3(32 * 64), 256, 0, stream>>>(qkv_buf, vT_buf, o_buf);

    // x2 = x + o @ proj_w + b   (overwrites vT region — vT dead by now)
    gemm_bt<2><<<dim3(1024 / 128, M / 128), 256, 0, stream>>>(
        o_buf, wpT, proj_b, x, x2_buf, nullptr, M, 1024, 1024);

    // LN2
    ln_kernel<<<M, 256, 0, stream>>>(x2_buf, h_buf);

    // g = gelu(h2 @ fc1_w + b) -> bf16
    gemm_bt<1><<<dim3(4096 / 128, M / 128), 256, 0, stream>>>(
        h_buf, w1T, fc1_b, nullptr, nullptr, g_buf, M, 4096, 1024);

    // out = x2 + g @ fc2_w + b
    gemm_bt<2><<<dim3(1024 / 128, M / 128), 256, 0, stream>>>(
        g_buf, w2T, fc2_b, x2_buf, out, nullptr, M, 1024, 4096);
}

// Round 4
// 504.809 us; speedup vs baseline: 1.5935x; 1.2475x over previous
//
#include <hip/hip_runtime.h>
#include <hip/hip_bf16.h>

typedef float f32x4 __attribute__((ext_vector_type(4)));
typedef __bf16 bf16x8 __attribute__((ext_vector_type(8)));
typedef unsigned short us8 __attribute__((ext_vector_type(8)));

#define MBYTE (1ull << 20)

// scale * log2(e): Q pre-scaled so attention logits are in log2 domain
#define QSCALE_LOG2E 0.18033688011112042f

__device__ __forceinline__ unsigned short f2bf(float f) {
    unsigned int u = __float_as_uint(f);
    u += 0x7fffu + ((u >> 16) & 1u);
    return (unsigned short)(u >> 16);
}

__device__ __forceinline__ float fast_exp2(float x) {
    return __builtin_amdgcn_exp2f(x);
}

__device__ __forceinline__ f32x4 mfma16(bf16x8 a, bf16x8 b, f32x4 c) {
    return __builtin_amdgcn_mfma_f32_16x16x32_bf16(a, b, c, 0, 0, 0);
}

// async global->LDS, 16B per lane, dest = wave-uniform base + lane*16
__device__ __forceinline__ void gload16(const void* g, void* l) {
    __builtin_amdgcn_global_load_lds(
        (const __attribute__((address_space(1))) unsigned int*)g,
        (__attribute__((address_space(3))) unsigned int*)l, 16, 0, 0);
}

// ---------------- LayerNorm: fp32 [rows][1024] -> bf16 ----------------
__global__ __launch_bounds__(256) void ln_kernel(const float* __restrict__ x,
                                                 unsigned short* __restrict__ out) {
    int row = blockIdx.x;
    int t = threadIdx.x;
    const float* xr = x + (size_t)row * 1024;
    float4 v = *(const float4*)(xr + t * 4);
    float s = v.x + v.y + v.z + v.w;
    float ss = v.x * v.x + v.y * v.y + v.z * v.z + v.w * v.w;
    #pragma unroll
    for (int off = 1; off < 64; off <<= 1) {
        s += __shfl_xor(s, off);
        ss += __shfl_xor(ss, off);
    }
    __shared__ float ps[4], pss[4];
    int wid = t >> 6, lane = t & 63;
    if (lane == 0) { ps[wid] = s; pss[wid] = ss; }
    __syncthreads();
    s = ps[0] + ps[1] + ps[2] + ps[3];
    ss = pss[0] + pss[1] + pss[2] + pss[3];
    float mean = s * (1.0f / 1024.0f);
    float var = ss * (1.0f / 1024.0f) - mean * mean;
    float rs = rsqrtf(var + 1e-6f);
    ushort4 ov;
    ov.x = f2bf((v.x - mean) * rs);
    ov.y = f2bf((v.y - mean) * rs);
    ov.z = f2bf((v.z - mean) * rs);
    ov.w = f2bf((v.w - mean) * rs);
    *(ushort4*)(out + (size_t)row * 1024 + t * 4) = ov;
}

// ------------- transpose + fp32->bf16: W[K][N] -> Wt[N][K] -------------
__global__ __launch_bounds__(256) void convT_kernel(const float* __restrict__ W,
                                                    unsigned short* __restrict__ Wt,
                                                    int K, int N) {
    __shared__ float tile[32][33];
    int t = threadIdx.x;
    int tx = t & 31, ty = t >> 5;  // ty 0..7
    int bx = blockIdx.x, by = blockIdx.y;
    #pragma unroll
    for (int r = 0; r < 4; r++) {
        int row = by * 32 + ty + r * 8;
        int col = bx * 32 + tx;
        tile[ty + r * 8][tx] = W[(size_t)row * N + col];
    }
    __syncthreads();
    #pragma unroll
    for (int r = 0; r < 4; r++) {
        int orow = bx * 32 + ty + r * 8;  // n
        int ocol = by * 32 + tx;          // k
        Wt[(size_t)orow * K + ocol] = f2bf(tile[tx][ty + r * 8]);
    }
}

// ------------- V transpose: qkv V-part bf16 -> vT[bh][64][2048] -------------
__global__ __launch_bounds__(256) void vT_kernel(const unsigned short* __restrict__ qkv,
                                                 unsigned short* __restrict__ vT) {
    __shared__ unsigned short tile[32][34];
    int t = threadIdx.x;
    int tx = t & 31, ty = t >> 5;  // ty 0..7
    int lt = blockIdx.x, dt = blockIdx.y, bh = blockIdx.z;
    int b = bh >> 4, h = bh & 15;
    const unsigned short* src = qkv + (size_t)(b * 2048 + lt * 32) * 3072 + 2048 + h * 64 + dt * 32;
    #pragma unroll
    for (int r = 0; r < 4; r++)
        tile[ty + r * 8][tx] = src[(size_t)(ty + r * 8) * 3072 + tx];
    __syncthreads();
    unsigned short* dst = vT + ((size_t)bh * 64 + dt * 32) * 2048 + (size_t)lt * 32;
    #pragma unroll
    for (int r = 0; r < 4; r++)
        dst[(size_t)(ty + r * 8) * 2048 + tx] = tile[tx][ty + r * 8];
}

// ------- GEMM (m97 structure): C[M][N] = A[M][K](bf16) @ Bt[N][K]^T -------
// global_load_lds width-16 staging into linear LDS, 2 barriers/K-step.
// EPI 0: outB = bf16(C + bias), cols<1024 scaled by QSCALE_LOG2E (q for attn)
// EPI 1: outB = bf16(gelu_tanh(C + bias))
// EPI 2: outF = C + bias + res
template <int EPI>
__global__ __launch_bounds__(256) void gemm_bt(const unsigned short* __restrict__ A,
                                               const unsigned short* __restrict__ Bt,
                                               const float* __restrict__ bias,
                                               const float* __restrict__ res,
                                               float* __restrict__ outF,
                                               unsigned short* __restrict__ outB,
                                               int M, int N, int K) {
    __shared__ __align__(16) unsigned short As[128 * 32];
    __shared__ __align__(16) unsigned short Bs[128 * 32];
    int t = threadIdx.x;
    int lane = t & 63, wid = t >> 6;

    // XCD-aware bijective swizzle (grid size % 8 == 0 for all our shapes)
    int gx = gridDim.x;
    int nwg = gx * gridDim.y;
    int orig = blockIdx.y * gx + blockIdx.x;
    int cpx = nwg >> 3;
    int swz = (orig & 7) * cpx + (orig >> 3);
    int bm = swz / gx, bn = swz % gx;

    int wm = wid >> 1, wn = wid & 1;
    f32x4 acc[4][4] = {};

    // staging addresses: wave w covers LDS rows [w*32, w*32+32)
    int sub = lane >> 2;        // row within 16
    int chunk = lane & 3;       // 16B chunk within 64B row
    const unsigned short* gA0 = A + (size_t)(bm * 128 + wid * 32 + sub) * K + chunk * 8;
    const unsigned short* gA1 = gA0 + (size_t)16 * K;
    const unsigned short* gB0 = Bt + (size_t)(bn * 128 + wid * 32 + sub) * K + chunk * 8;
    const unsigned short* gB1 = gB0 + (size_t)16 * K;
    unsigned short* lA0 = &As[(wid * 32) * 32];
    unsigned short* lA1 = &As[(wid * 32 + 16) * 32];
    unsigned short* lB0 = &Bs[(wid * 32) * 32];
    unsigned short* lB1 = &Bs[(wid * 32 + 16) * 32];

    for (int k0 = 0; k0 < K; k0 += 32) {
        __syncthreads();
        gload16(gA0 + k0, lA0);
        gload16(gA1 + k0, lA1);
        gload16(gB0 + k0, lB0);
        gload16(gB1 + k0, lB1);
        __syncthreads();
        bf16x8 af[4], bfr[4];
        #pragma unroll
        for (int m = 0; m < 4; m++)
            af[m] = *(const bf16x8*)&As[(wm * 64 + m * 16 + (lane & 15)) * 32 + (lane >> 4) * 8];
        #pragma unroll
        for (int n = 0; n < 4; n++)
            bfr[n] = *(const bf16x8*)&Bs[(wn * 64 + n * 16 + (lane & 15)) * 32 + (lane >> 4) * 8];
        #pragma unroll
        for (int m = 0; m < 4; m++)
            #pragma unroll
            for (int n = 0; n < 4; n++)
                acc[m][n] = mfma16(af[m], bfr[n], acc[m][n]);
    }

    #pragma unroll
    for (int m = 0; m < 4; m++) {
        #pragma unroll
        for (int n = 0; n < 4; n++) {
            int col = bn * 128 + wn * 64 + n * 16 + (lane & 15);
            float bv = bias[col];
            #pragma unroll
            for (int r = 0; r < 4; r++) {
                int row = bm * 128 + wm * 64 + m * 16 + (lane >> 4) * 4 + r;
                float val = acc[m][n][r] + bv;
                if (EPI == 0) {
                    if (col < 1024) val *= QSCALE_LOG2E;  // pre-scale q
                    outB[(size_t)row * N + col] = f2bf(val);
                } else if (EPI == 1) {
                    float g = 0.5f * val *
                              (1.0f + tanhf(0.7978845608028654f *
                                            (val + 0.044715f * val * val * val)));
                    outB[(size_t)row * N + col] = f2bf(g);
                } else {
                    outF[(size_t)row * N + col] = val + res[(size_t)row * N + col];
                }
            }
        }
    }
}

// ---------------- Flash attention v3 (defer-max, log2 domain) ----------------
// qkv bf16 [B*L][3*16*64] (q pre-scaled by QSCALE_LOG2E); vT bf16 [bh][64][2048];
// o bf16 [B*L][1024]. grid: 32 qtiles * 64 bh; 256 thr; wave owns 16 q rows.
__global__ __launch_bounds__(256) void attn_kernel(const unsigned short* __restrict__ qkv,
                                                   const unsigned short* __restrict__ vT,
                                                   unsigned short* __restrict__ o) {
    int bid = blockIdx.x;
    int qb = bid & 31;       // q tile (64 rows)
    int bh = bid >> 5;
    int b = bh >> 4, h = bh & 15;
    int t = threadIdx.x, lane = t & 63, wid = t >> 6;

    const unsigned short* base = qkv + (size_t)b * 2048 * 3072 + h * 64;
    const unsigned short* vbase = vT + (size_t)bh * 64 * 2048;

    __shared__ __align__(16) unsigned short Ks[64][72];    // [key][d]
    __shared__ __align__(16) unsigned short Vs[64][72];    // [d][key]
    __shared__ __align__(16) unsigned short Pw[4][16][72]; // per-wave P [q][key]

    bf16x8 aq[2];
    {
        int qrow = qb * 64 + wid * 16 + (lane & 15);
        const unsigned short* qp = base + (size_t)qrow * 3072 + (lane >> 4) * 8;
        aq[0] = *(const bf16x8*)(qp);
        aq[1] = *(const bf16x8*)(qp + 32);
    }

    float m_r[4], lpart[4];
    f32x4 accO[4] = {};
    #pragma unroll
    for (int r = 0; r < 4; r++) { m_r[r] = -1e30f; lpart[r] = 0.0f; }

    int srow = t >> 2;          // 0..63
    int scol = (t & 3) * 16;    // 0..48

    for (int kt = 0; kt < 32; kt++) {
        __syncthreads();
        const unsigned short* kp = base + 1024 + (size_t)(kt * 64 + srow) * 3072 + scol;
        const unsigned short* vp = vbase + (size_t)srow * 2048 + kt * 64 + scol;
        us8 k0 = *(const us8*)kp;
        us8 k1 = *(const us8*)(kp + 8);
        us8 v0 = *(const us8*)vp;
        us8 v1 = *(const us8*)(vp + 8);
        *(us8*)&Ks[srow][scol] = k0;
        *(us8*)&Ks[srow][scol + 8] = k1;
        *(us8*)&Vs[srow][scol] = v0;
        *(us8*)&Vs[srow][scol + 8] = v1;
        __syncthreads();

        // S = Q @ K^T (log2 domain; q pre-scaled)
        f32x4 s[4] = {};
        #pragma unroll
        for (int nf = 0; nf < 4; nf++) {
            #pragma unroll
            for (int c = 0; c < 2; c++) {
                bf16x8 bk = *(const bf16x8*)&Ks[nf * 16 + (lane & 15)][c * 32 + (lane >> 4) * 8];
                s[nf] = mfma16(aq[c], bk, s[nf]);
            }
        }

        // defer-max online softmax: fast path has NO cross-lane ops
        float mx[4];
        #pragma unroll
        for (int r = 0; r < 4; r++)
            mx[r] = fmaxf(fmaxf(s[0][r], s[1][r]), fmaxf(s[2][r], s[3][r]));
        bool ok = (mx[0] <= m_r[0] + 8.0f) && (mx[1] <= m_r[1] + 8.0f) &&
                  (mx[2] <= m_r[2] + 8.0f) && (mx[3] <= m_r[3] + 8.0f);
        if (!__all(ok)) {
            // slow path: true row max, rescale running state
            #pragma unroll
            for (int r = 0; r < 4; r++) {
                float mm = mx[r];
                #pragma unroll
                for (int off = 1; off < 16; off <<= 1) mm = fmaxf(mm, __shfl_xor(mm, off));
                float mnew = fmaxf(m_r[r], mm);
                float corr = fast_exp2(m_r[r] - mnew);
                m_r[r] = mnew;
                lpart[r] *= corr;
                #pragma unroll
                for (int nn = 0; nn < 4; nn++) accO[nn][r] *= corr;
            }
        }
        // exp2 + per-lane partial sum + P write
        #pragma unroll
        for (int r = 0; r < 4; r++) {
            float p0 = fast_exp2(s[0][r] - m_r[r]);
            float p1 = fast_exp2(s[1][r] - m_r[r]);
            float p2 = fast_exp2(s[2][r] - m_r[r]);
            float p3 = fast_exp2(s[3][r] - m_r[r]);
            lpart[r] += (p0 + p1) + (p2 + p3);
            int prow = (lane >> 4) * 4 + r, pcol = lane & 15;
            Pw[wid][prow][pcol] = f2bf(p0);
            Pw[wid][prow][16 + pcol] = f2bf(p1);
            Pw[wid][prow][32 + pcol] = f2bf(p2);
            Pw[wid][prow][48 + pcol] = f2bf(p3);
        }

        // PV: O[q][d] += P[q][k] * V[k][d]
        #pragma unroll
        for (int kg = 0; kg < 2; kg++) {
            bf16x8 pa = *(const bf16x8*)&Pw[wid][lane & 15][kg * 32 + (lane >> 4) * 8];
            #pragma unroll
            for (int nn = 0; nn < 4; nn++) {
                bf16x8 bv = *(const bf16x8*)&Vs[nn * 16 + (lane & 15)][kg * 32 + (lane >> 4) * 8];
                accO[nn] = mfma16(pa, bv, accO[nn]);
            }
        }
    }

    // final: reduce per-lane partial sums across the 16-lane row group
    float rinv[4];
    #pragma unroll
    for (int r = 0; r < 4; r++) {
        float rs = lpart[r];
        #pragma unroll
        for (int off = 1; off < 16; off <<= 1) rs += __shfl_xor(rs, off);
        rinv[r] = 1.0f / rs;
    }
    #pragma unroll
    for (int nn = 0; nn < 4; nn++) {
        int col = h * 64 + nn * 16 + (lane & 15);
        #pragma unroll
        for (int r = 0; r < 4; r++) {
            int row = qb * 64 + wid * 16 + (lane >> 4) * 4 + r;
            o[(size_t)(b * 2048 + row) * 1024 + col] = f2bf(accO[nn][r] * rinv[r]);
        }
    }
}

extern "C" void kernel_launch(void* const* d_in, const int* in_sizes, int n_in,
                              void* d_out, int out_size, void* d_ws, size_t ws_size,
                              hipStream_t stream) {
    const float* x      = (const float*)d_in[0];
    const float* qkv_w  = (const float*)d_in[1];
    const float* qkv_b  = (const float*)d_in[2];
    const float* proj_w = (const float*)d_in[3];
    const float* proj_b = (const float*)d_in[4];
    const float* fc1_w  = (const float*)d_in[5];
    const float* fc1_b  = (const float*)d_in[6];
    const float* fc2_w  = (const float*)d_in[7];
    const float* fc2_b  = (const float*)d_in[8];
    float* out = (float*)d_out;

    char* ws = (char*)d_ws;
    unsigned short* h_buf   = (unsigned short*)(ws + 0 * MBYTE);    // 16 MB (reused for h2)
    unsigned short* qkv_buf = (unsigned short*)(ws + 16 * MBYTE);   // 48 MB
    unsigned short* o_buf   = (unsigned short*)(ws + 64 * MBYTE);   // 16 MB
    float*          x2_buf  = (float*)(ws + 80 * MBYTE);            // 32 MB
    unsigned short* vT_buf  = (unsigned short*)(ws + 80 * MBYTE);   // 17 MB (dead before x2 written)
    unsigned short* wqT     = (unsigned short*)(ws + 112 * MBYTE);  // 6 MB
    unsigned short* wpT     = (unsigned short*)(ws + 118 * MBYTE);  // 2 MB
    unsigned short* w1T     = (unsigned short*)(ws + 120 * MBYTE);  // 8 MB
    unsigned short* w2T     = (unsigned short*)(ws + 128 * MBYTE);  // 8 MB
    unsigned short* g_buf   = (unsigned short*)(ws + 16 * MBYTE);   // 64 MB (reuse qkv+o)

    const int M = 8192;  // B*L

    convT_kernel<<<dim3(3072 / 32, 1024 / 32), 256, 0, stream>>>(qkv_w, wqT, 1024, 3072);
    convT_kernel<<<dim3(1024 / 32, 1024 / 32), 256, 0, stream>>>(proj_w, wpT, 1024, 1024);
    convT_kernel<<<dim3(4096 / 32, 1024 / 32), 256, 0, stream>>>(fc1_w, w1T, 1024, 4096);
    convT_kernel<<<dim3(1024 / 32, 4096 / 32), 256, 0, stream>>>(fc2_w, w2T, 4096, 1024);

    ln_kernel<<<M, 256, 0, stream>>>(x, h_buf);

    gemm_bt<0><<<dim3(3072 / 128, M / 128), 256, 0, stream>>>(
        h_buf, wqT, qkv_b, nullptr, nullptr, qkv_buf, M, 3072, 1024);

    vT_kernel<<<dim3(64, 2, 64), 256, 0, stream>>>(qkv_buf, vT_buf);

    attn_kernel<<<dim3(32 * 64), 256, 0, stream>>>(qkv_buf, vT_buf, o_buf);

    gemm_bt<2><<<dim3(1024 / 128, M / 128), 256, 0, stream>>>(
        o_buf, wpT, proj_b, x, x2_buf, nullptr, M, 1024, 1024);

    ln_kernel<<<M, 256, 0, stream>>>(x2_buf, h_buf);

    gemm_bt<1><<<dim3(4096 / 128, M / 128), 256, 0, stream>>>(
        h_buf, w1T, fc1_b, nullptr, nullptr, g_buf, M, 4096, 1024);

    gemm_bt<2><<<dim3(1024 / 128, M / 128), 256, 0, stream>>>(
        g_buf, w2T, fc2_b, x2_buf, out, nullptr, M, 1024, 4096);
}

// Round 5
// 481.748 us; speedup vs baseline: 1.6698x; 1.0479x over previous
//
#include <hip/hip_runtime.h>
#include <hip/hip_bf16.h>

typedef float f32x4 __attribute__((ext_vector_type(4)));
typedef __bf16 bf16x8 __attribute__((ext_vector_type(8)));
typedef unsigned short us8 __attribute__((ext_vector_type(8)));

#define MBYTE (1ull << 20)

// scale * log2(e): Q pre-scaled so attention logits are in log2 domain
#define QSCALE_LOG2E 0.18033688011112042f

__device__ __forceinline__ unsigned short f2bf(float f) {
    unsigned int u = __float_as_uint(f);
    u += 0x7fffu + ((u >> 16) & 1u);
    return (unsigned short)(u >> 16);
}

__device__ __forceinline__ float fast_exp2(float x) {
    return __builtin_amdgcn_exp2f(x);
}

__device__ __forceinline__ f32x4 mfma16(bf16x8 a, bf16x8 b, f32x4 c) {
    return __builtin_amdgcn_mfma_f32_16x16x32_bf16(a, b, c, 0, 0, 0);
}

// async global->LDS, 16B per lane, dest = wave-uniform base + lane*16
__device__ __forceinline__ void gload16(const void* g, void* l) {
    __builtin_amdgcn_global_load_lds(
        (const __attribute__((address_space(1))) unsigned int*)g,
        (__attribute__((address_space(3))) unsigned int*)l, 16, 0, 0);
}

// ---------------- LayerNorm: fp32 [rows][1024] -> bf16 ----------------
__global__ __launch_bounds__(256) void ln_kernel(const float* __restrict__ x,
                                                 unsigned short* __restrict__ out) {
    int row = blockIdx.x;
    int t = threadIdx.x;
    const float* xr = x + (size_t)row * 1024;
    float4 v = *(const float4*)(xr + t * 4);
    float s = v.x + v.y + v.z + v.w;
    float ss = v.x * v.x + v.y * v.y + v.z * v.z + v.w * v.w;
    #pragma unroll
    for (int off = 1; off < 64; off <<= 1) {
        s += __shfl_xor(s, off);
        ss += __shfl_xor(ss, off);
    }
    __shared__ float ps[4], pss[4];
    int wid = t >> 6, lane = t & 63;
    if (lane == 0) { ps[wid] = s; pss[wid] = ss; }
    __syncthreads();
    s = ps[0] + ps[1] + ps[2] + ps[3];
    ss = pss[0] + pss[1] + pss[2] + pss[3];
    float mean = s * (1.0f / 1024.0f);
    float var = ss * (1.0f / 1024.0f) - mean * mean;
    float rs = rsqrtf(var + 1e-6f);
    ushort4 ov;
    ov.x = f2bf((v.x - mean) * rs);
    ov.y = f2bf((v.y - mean) * rs);
    ov.z = f2bf((v.z - mean) * rs);
    ov.w = f2bf((v.w - mean) * rs);
    *(ushort4*)(out + (size_t)row * 1024 + t * 4) = ov;
}

// ------------- transpose + fp32->bf16: W[K][N] -> Wt[N][K] -------------
__global__ __launch_bounds__(256) void convT_kernel(const float* __restrict__ W,
                                                    unsigned short* __restrict__ Wt,
                                                    int K, int N) {
    __shared__ float tile[32][33];
    int t = threadIdx.x;
    int tx = t & 31, ty = t >> 5;  // ty 0..7
    int bx = blockIdx.x, by = blockIdx.y;
    #pragma unroll
    for (int r = 0; r < 4; r++) {
        int row = by * 32 + ty + r * 8;
        int col = bx * 32 + tx;
        tile[ty + r * 8][tx] = W[(size_t)row * N + col];
    }
    __syncthreads();
    #pragma unroll
    for (int r = 0; r < 4; r++) {
        int orow = bx * 32 + ty + r * 8;  // n
        int ocol = by * 32 + tx;          // k
        Wt[(size_t)orow * K + ocol] = f2bf(tile[tx][ty + r * 8]);
    }
}

// ------------- V transpose: qkv V-part bf16 -> vT[bh][64][2048] -------------
// Key axis is PERMUTED within each 64-key tile so that the attention kernel's
// in-register P fragments line up with V columns:
//   orig key (nf,hi,r) = nf*16 + hi*4 + r  ->  (nf>>1)*32 + hi*8 + (nf&1)*4 + r
__global__ __launch_bounds__(256) void vT_kernel(const unsigned short* __restrict__ qkv,
                                                 unsigned short* __restrict__ vT) {
    __shared__ unsigned short tile[32][34];
    int t = threadIdx.x;
    int tx = t & 31, ty = t >> 5;  // ty 0..7
    int lt = blockIdx.x, dt = blockIdx.y, bh = blockIdx.z;
    int b = bh >> 4, h = bh & 15;
    const unsigned short* src = qkv + (size_t)(b * 2048 + lt * 32) * 3072 + 2048 + h * 64 + dt * 32;
    #pragma unroll
    for (int r = 0; r < 4; r++)
        tile[ty + r * 8][tx] = src[(size_t)(ty + r * 8) * 3072 + tx];
    __syncthreads();
    // permuted column within the 64-key tile
    int perm = (lt & 1) * 32 + ((tx >> 2) & 3) * 8 + ((tx >> 4) & 1) * 4 + (tx & 3);
    unsigned short* dst = vT + ((size_t)bh * 64 + dt * 32) * 2048 + (size_t)(lt >> 1) * 64;
    #pragma unroll
    for (int r = 0; r < 4; r++)
        dst[(size_t)(ty + r * 8) * 2048 + perm] = tile[tx][ty + r * 8];
}

// ------- GEMM (m97 structure): C[M][N] = A[M][K](bf16) @ Bt[N][K]^T -------
template <int EPI>
__global__ __launch_bounds__(256) void gemm_bt(const unsigned short* __restrict__ A,
                                               const unsigned short* __restrict__ Bt,
                                               const float* __restrict__ bias,
                                               const float* __restrict__ res,
                                               float* __restrict__ outF,
                                               unsigned short* __restrict__ outB,
                                               int M, int N, int K) {
    __shared__ __align__(16) unsigned short As[128 * 32];
    __shared__ __align__(16) unsigned short Bs[128 * 32];
    int t = threadIdx.x;
    int lane = t & 63, wid = t >> 6;

    // XCD-aware bijective swizzle (grid size % 8 == 0 for all our shapes)
    int gx = gridDim.x;
    int nwg = gx * gridDim.y;
    int orig = blockIdx.y * gx + blockIdx.x;
    int cpx = nwg >> 3;
    int swz = (orig & 7) * cpx + (orig >> 3);
    int bm = swz / gx, bn = swz % gx;

    int wm = wid >> 1, wn = wid & 1;
    f32x4 acc[4][4] = {};

    int sub = lane >> 2;        // row within 16
    int chunk = lane & 3;       // 16B chunk within 64B row
    const unsigned short* gA0 = A + (size_t)(bm * 128 + wid * 32 + sub) * K + chunk * 8;
    const unsigned short* gA1 = gA0 + (size_t)16 * K;
    const unsigned short* gB0 = Bt + (size_t)(bn * 128 + wid * 32 + sub) * K + chunk * 8;
    const unsigned short* gB1 = gB0 + (size_t)16 * K;
    unsigned short* lA0 = &As[(wid * 32) * 32];
    unsigned short* lA1 = &As[(wid * 32 + 16) * 32];
    unsigned short* lB0 = &Bs[(wid * 32) * 32];
    unsigned short* lB1 = &Bs[(wid * 32 + 16) * 32];

    for (int k0 = 0; k0 < K; k0 += 32) {
        __syncthreads();
        gload16(gA0 + k0, lA0);
        gload16(gA1 + k0, lA1);
        gload16(gB0 + k0, lB0);
        gload16(gB1 + k0, lB1);
        __syncthreads();
        bf16x8 af[4], bfr[4];
        #pragma unroll
        for (int m = 0; m < 4; m++)
            af[m] = *(const bf16x8*)&As[(wm * 64 + m * 16 + (lane & 15)) * 32 + (lane >> 4) * 8];
        #pragma unroll
        for (int n = 0; n < 4; n++)
            bfr[n] = *(const bf16x8*)&Bs[(wn * 64 + n * 16 + (lane & 15)) * 32 + (lane >> 4) * 8];
        #pragma unroll
        for (int m = 0; m < 4; m++)
            #pragma unroll
            for (int n = 0; n < 4; n++)
                acc[m][n] = mfma16(af[m], bfr[n], acc[m][n]);
    }

    #pragma unroll
    for (int m = 0; m < 4; m++) {
        #pragma unroll
        for (int n = 0; n < 4; n++) {
            int col = bn * 128 + wn * 64 + n * 16 + (lane & 15);
            float bv = bias[col];
            #pragma unroll
            for (int r = 0; r < 4; r++) {
                int row = bm * 128 + wm * 64 + m * 16 + (lane >> 4) * 4 + r;
                float val = acc[m][n][r] + bv;
                if (EPI == 0) {
                    if (col < 1024) val *= QSCALE_LOG2E;  // pre-scale q
                    outB[(size_t)row * N + col] = f2bf(val);
                } else if (EPI == 1) {
                    float g = 0.5f * val *
                              (1.0f + tanhf(0.7978845608028654f *
                                            (val + 0.044715f * val * val * val)));
                    outB[(size_t)row * N + col] = f2bf(g);
                } else {
                    outF[(size_t)row * N + col] = val + res[(size_t)row * N + col];
                }
            }
        }
    }
}

// ------- Flash attention v4: swapped QK^T, in-register P, no P LDS -------
// qkv bf16 [B*L][3*16*64] (q pre-scaled by QSCALE_LOG2E);
// vT bf16 [bh][64][2048] with key axis permuted per vT_kernel;
// o bf16 [B*L][1024]. grid: 32 qtiles * 64 bh; 256 thr; wave owns 16 q rows.
__global__ __launch_bounds__(256) void attn_kernel(const unsigned short* __restrict__ qkv,
                                                   const unsigned short* __restrict__ vT,
                                                   unsigned short* __restrict__ o) {
    int bid = blockIdx.x;
    int qb = bid & 31;
    int bh = bid >> 5;
    int b = bh >> 4, h = bh & 15;
    int t = threadIdx.x, lane = t & 63, wid = t >> 6;

    const unsigned short* base = qkv + (size_t)b * 2048 * 3072 + h * 64;
    const unsigned short* vbase = vT + (size_t)bh * 64 * 2048;

    __shared__ __align__(16) unsigned short Ks[64][72];  // [key][d]
    __shared__ __align__(16) unsigned short Vs[64][72];  // [d][key'] (permuted)

    int ql = lane & 15;   // q row within wave (also key-row / d-col sub-index)
    int hi = lane >> 4;   // 0..3

    // Q fragments as MFMA B-operand: lane holds Q[q=ql][d=hi*8+j (+32c)]
    bf16x8 qf[2];
    {
        int qrow = qb * 64 + wid * 16 + ql;
        const unsigned short* qp = base + (size_t)qrow * 3072 + hi * 8;
        qf[0] = *(const bf16x8*)(qp);
        qf[1] = *(const bf16x8*)(qp + 32);
    }

    float m_r = -1e30f, lpart = 0.0f;
    f32x4 accO[4] = {};

    int srow = t >> 2;          // 0..63
    int scol = (t & 3) * 16;    // 0..48
    const unsigned short* kp = base + 1024 + (size_t)srow * 3072 + scol;
    const unsigned short* vp = vbase + (size_t)srow * 2048 + scol;

    // T14: prologue loads tile 0 into regs
    us8 kr0 = *(const us8*)kp;
    us8 kr1 = *(const us8*)(kp + 8);
    us8 vr0 = *(const us8*)vp;
    us8 vr1 = *(const us8*)(vp + 8);

    for (int kt = 0; kt < 32; kt++) {
        __syncthreads();
        *(us8*)&Ks[srow][scol] = kr0;
        *(us8*)&Ks[srow][scol + 8] = kr1;
        *(us8*)&Vs[srow][scol] = vr0;
        *(us8*)&Vs[srow][scol + 8] = vr1;
        if (kt + 1 < 32) {  // issue next tile's loads; land under compute
            const unsigned short* kpn = kp + (size_t)(kt + 1) * 64 * 3072;
            const unsigned short* vpn = vp + (kt + 1) * 64;
            kr0 = *(const us8*)kpn;
            kr1 = *(const us8*)(kpn + 8);
            vr0 = *(const us8*)vpn;
            vr1 = *(const us8*)(vpn + 8);
        }
        __syncthreads();

        // swapped QK^T: s[nf] = S^T frag; lane holds q=ql, keys nf*16+hi*4+r
        f32x4 s0 = {}, s1 = {}, s2 = {}, s3 = {};
        #pragma unroll
        for (int c = 0; c < 2; c++) {
            bf16x8 a0 = *(const bf16x8*)&Ks[ 0 + ql][c * 32 + hi * 8];
            bf16x8 a1 = *(const bf16x8*)&Ks[16 + ql][c * 32 + hi * 8];
            bf16x8 a2 = *(const bf16x8*)&Ks[32 + ql][c * 32 + hi * 8];
            bf16x8 a3 = *(const bf16x8*)&Ks[48 + ql][c * 32 + hi * 8];
            s0 = mfma16(a0, qf[c], s0);
            s1 = mfma16(a1, qf[c], s1);
            s2 = mfma16(a2, qf[c], s2);
            s3 = mfma16(a3, qf[c], s3);
        }

        // defer-max: lane-local 16-value max; slow path only on threshold break
        float mx = fmaxf(fmaxf(fmaxf(s0[0], s0[1]), fmaxf(s0[2], s0[3])),
                         fmaxf(fmaxf(s1[0], s1[1]), fmaxf(s1[2], s1[3])));
        mx = fmaxf(mx, fmaxf(fmaxf(s2[0], s2[1]), fmaxf(s2[2], s2[3])));
        mx = fmaxf(mx, fmaxf(fmaxf(s3[0], s3[1]), fmaxf(s3[2], s3[3])));
        if (!__all(mx <= m_r + 8.0f)) {   // wave-uniform branch
            float mm = fmaxf(mx, __shfl_xor(mx, 16));
            mm = fmaxf(mm, __shfl_xor(mm, 32));
            float mnew = fmaxf(m_r, mm);
            float corr = fast_exp2(m_r - mnew);
            m_r = mnew;
            lpart *= corr;
            #pragma unroll
            for (int r = 0; r < 4; r++) {
                float cq = __shfl(corr, hi * 4 + r);  // corr for q_out=hi*4+r
                accO[0][r] *= cq; accO[1][r] *= cq;
                accO[2][r] *= cq; accO[3][r] *= cq;
            }
        }

        // exp2 -> packed PV A-fragments (in-register, zero cross-lane)
        us8 pu0, pu1;
        #pragma unroll
        for (int j = 0; j < 4; j++) {
            float pa = fast_exp2(s0[j] - m_r);
            float pb = fast_exp2(s1[j] - m_r);
            float pc = fast_exp2(s2[j] - m_r);
            float pd = fast_exp2(s3[j] - m_r);
            lpart += (pa + pb) + (pc + pd);
            pu0[j] = f2bf(pa); pu0[4 + j] = f2bf(pb);
            pu1[j] = f2bf(pc); pu1[4 + j] = f2bf(pd);
        }
        bf16x8 paf0 = __builtin_bit_cast(bf16x8, pu0);
        bf16x8 paf1 = __builtin_bit_cast(bf16x8, pu1);

        // PV: accO[nn] += P[q][key'] * V[key'][d]  (key' = permuted axis)
        #pragma unroll
        for (int nn = 0; nn < 4; nn++) {
            bf16x8 bv0 = *(const bf16x8*)&Vs[nn * 16 + ql][hi * 8];
            bf16x8 bv1 = *(const bf16x8*)&Vs[nn * 16 + ql][32 + hi * 8];
            accO[nn] = mfma16(paf0, bv0, accO[nn]);
            accO[nn] = mfma16(paf1, bv1, accO[nn]);
        }
    }

    // final: sum per-lane partials across the 4 key-lanes of each q
    lpart += __shfl_xor(lpart, 16);
    lpart += __shfl_xor(lpart, 32);
    float rinv = 1.0f / lpart;
    #pragma unroll
    for (int r = 0; r < 4; r++) {
        float rq = __shfl(rinv, hi * 4 + r);
        int row = qb * 64 + wid * 16 + hi * 4 + r;
        #pragma unroll
        for (int nn = 0; nn < 4; nn++) {
            int col = h * 64 + nn * 16 + ql;
            o[(size_t)(b * 2048 + row) * 1024 + col] = f2bf(accO[nn][r] * rq);
        }
    }
}

extern "C" void kernel_launch(void* const* d_in, const int* in_sizes, int n_in,
                              void* d_out, int out_size, void* d_ws, size_t ws_size,
                              hipStream_t stream) {
    const float* x      = (const float*)d_in[0];
    const float* qkv_w  = (const float*)d_in[1];
    const float* qkv_b  = (const float*)d_in[2];
    const float* proj_w = (const float*)d_in[3];
    const float* proj_b = (const float*)d_in[4];
    const float* fc1_w  = (const float*)d_in[5];
    const float* fc1_b  = (const float*)d_in[6];
    const float* fc2_w  = (const float*)d_in[7];
    const float* fc2_b  = (const float*)d_in[8];
    float* out = (float*)d_out;

    char* ws = (char*)d_ws;
    unsigned short* h_buf   = (unsigned short*)(ws + 0 * MBYTE);    // 16 MB (reused for h2)
    unsigned short* qkv_buf = (unsigned short*)(ws + 16 * MBYTE);   // 48 MB
    unsigned short* o_buf   = (unsigned short*)(ws + 64 * MBYTE);   // 16 MB
    float*          x2_buf  = (float*)(ws + 80 * MBYTE);            // 32 MB
    unsigned short* vT_buf  = (unsigned short*)(ws + 80 * MBYTE);   // 17 MB (dead before x2 written)
    unsigned short* wqT     = (unsigned short*)(ws + 112 * MBYTE);  // 6 MB
    unsigned short* wpT     = (unsigned short*)(ws + 118 * MBYTE);  // 2 MB
    unsigned short* w1T     = (unsigned short*)(ws + 120 * MBYTE);  // 8 MB
    unsigned short* w2T     = (unsigned short*)(ws + 128 * MBYTE);  // 8 MB
    unsigned short* g_buf   = (unsigned short*)(ws + 16 * MBYTE);   // 64 MB (reuse qkv+o)

    const int M = 8192;  // B*L

    convT_kernel<<<dim3(3072 / 32, 1024 / 32), 256, 0, stream>>>(qkv_w, wqT, 1024, 3072);
    convT_kernel<<<dim3(1024 / 32, 1024 / 32), 256, 0, stream>>>(proj_w, wpT, 1024, 1024);
    convT_kernel<<<dim3(4096 / 32, 1024 / 32), 256, 0, stream>>>(fc1_w, w1T, 1024, 4096);
    convT_kernel<<<dim3(1024 / 32, 4096 / 32), 256, 0, stream>>>(fc2_w, w2T, 4096, 1024);

    ln_kernel<<<M, 256, 0, stream>>>(x, h_buf);

    gemm_bt<0><<<dim3(3072 / 128, M / 128), 256, 0, stream>>>(
        h_buf, wqT, qkv_b, nullptr, nullptr, qkv_buf, M, 3072, 1024);

    vT_kernel<<<dim3(64, 2, 64), 256, 0, stream>>>(qkv_buf, vT_buf);

    attn_kernel<<<dim3(32 * 64), 256, 0, stream>>>(qkv_buf, vT_buf, o_buf);

    gemm_bt<2><<<dim3(1024 / 128, M / 128), 256, 0, stream>>>(
        o_buf, wpT, proj_b, x, x2_buf, nullptr, M, 1024, 1024);

    ln_kernel<<<M, 256, 0, stream>>>(x2_buf, h_buf);

    gemm_bt<1><<<dim3(4096 / 128, M / 128), 256, 0, stream>>>(
        h_buf, w1T, fc1_b, nullptr, nullptr, g_buf, M, 4096, 1024);

    gemm_bt<2><<<dim3(1024 / 128, M / 128), 256, 0, stream>>>(
        g_buf, w2T, fc2_b, x2_buf, out, nullptr, M, 1024, 4096);
}

// Round 6
// 472.384 us; speedup vs baseline: 1.7029x; 1.0198x over previous
//
#include <hip/hip_runtime.h>
#include <hip/hip_bf16.h>

typedef float f32x4 __attribute__((ext_vector_type(4)));
typedef __bf16 bf16x8 __attribute__((ext_vector_type(8)));
typedef unsigned short us8 __attribute__((ext_vector_type(8)));

#define MBYTE (1ull << 20)

// scale * log2(e): Q pre-scaled so attention logits are in log2 domain
#define QSCALE_LOG2E 0.18033688011112042f

__device__ __forceinline__ unsigned short f2bf(float f) {
    __bf16 h = (__bf16)f;   // native cvt (RTNE), cheap on gfx950
    return __builtin_bit_cast(unsigned short, h);
}

__device__ __forceinline__ float fast_exp2(float x) {
    return __builtin_amdgcn_exp2f(x);
}

__device__ __forceinline__ f32x4 mfma16(bf16x8 a, bf16x8 b, f32x4 c) {
    return __builtin_amdgcn_mfma_f32_16x16x32_bf16(a, b, c, 0, 0, 0);
}

// async global->LDS, 16B per lane, dest = wave-uniform base + lane*16
__device__ __forceinline__ void gload16(const void* g, void* l) {
    __builtin_amdgcn_global_load_lds(
        (const __attribute__((address_space(1))) unsigned int*)g,
        (__attribute__((address_space(3))) unsigned int*)l, 16, 0, 0);
}

// ---------------- LayerNorm: fp32 [rows][1024] -> bf16 ----------------
__global__ __launch_bounds__(256) void ln_kernel(const float* __restrict__ x,
                                                 unsigned short* __restrict__ out) {
    int row = blockIdx.x;
    int t = threadIdx.x;
    const float* xr = x + (size_t)row * 1024;
    float4 v = *(const float4*)(xr + t * 4);
    float s = v.x + v.y + v.z + v.w;
    float ss = v.x * v.x + v.y * v.y + v.z * v.z + v.w * v.w;
    #pragma unroll
    for (int off = 1; off < 64; off <<= 1) {
        s += __shfl_xor(s, off);
        ss += __shfl_xor(ss, off);
    }
    __shared__ float ps[4], pss[4];
    int wid = t >> 6, lane = t & 63;
    if (lane == 0) { ps[wid] = s; pss[wid] = ss; }
    __syncthreads();
    s = ps[0] + ps[1] + ps[2] + ps[3];
    ss = pss[0] + pss[1] + pss[2] + pss[3];
    float mean = s * (1.0f / 1024.0f);
    float var = ss * (1.0f / 1024.0f) - mean * mean;
    float rs = rsqrtf(var + 1e-6f);
    ushort4 ov;
    ov.x = f2bf((v.x - mean) * rs);
    ov.y = f2bf((v.y - mean) * rs);
    ov.z = f2bf((v.z - mean) * rs);
    ov.w = f2bf((v.w - mean) * rs);
    *(ushort4*)(out + (size_t)row * 1024 + t * 4) = ov;
}

// ------------- transpose + fp32->bf16: W[K][N] -> Wt[N][K] -------------
__global__ __launch_bounds__(256) void convT_kernel(const float* __restrict__ W,
                                                    unsigned short* __restrict__ Wt,
                                                    int K, int N) {
    __shared__ float tile[32][33];
    int t = threadIdx.x;
    int tx = t & 31, ty = t >> 5;  // ty 0..7
    int bx = blockIdx.x, by = blockIdx.y;
    #pragma unroll
    for (int r = 0; r < 4; r++) {
        int row = by * 32 + ty + r * 8;
        int col = bx * 32 + tx;
        tile[ty + r * 8][tx] = W[(size_t)row * N + col];
    }
    __syncthreads();
    #pragma unroll
    for (int r = 0; r < 4; r++) {
        int orow = bx * 32 + ty + r * 8;  // n
        int ocol = by * 32 + tx;          // k
        Wt[(size_t)orow * K + ocol] = f2bf(tile[tx][ty + r * 8]);
    }
}

// ------------- V transpose: qkv V-part bf16 -> vT[bh][64][2048] -------------
// Key axis is PERMUTED within each 64-key tile so that the attention kernel's
// in-register P fragments line up with V columns:
//   orig key (nf,hi,r) = nf*16 + hi*4 + r  ->  (nf>>1)*32 + hi*8 + (nf&1)*4 + r
__global__ __launch_bounds__(256) void vT_kernel(const unsigned short* __restrict__ qkv,
                                                 unsigned short* __restrict__ vT) {
    __shared__ unsigned short tile[32][34];
    int t = threadIdx.x;
    int tx = t & 31, ty = t >> 5;  // ty 0..7
    int lt = blockIdx.x, dt = blockIdx.y, bh = blockIdx.z;
    int b = bh >> 4, h = bh & 15;
    const unsigned short* src = qkv + (size_t)(b * 2048 + lt * 32) * 3072 + 2048 + h * 64 + dt * 32;
    #pragma unroll
    for (int r = 0; r < 4; r++)
        tile[ty + r * 8][tx] = src[(size_t)(ty + r * 8) * 3072 + tx];
    __syncthreads();
    // permuted column within the 64-key tile
    int perm = (lt & 1) * 32 + ((tx >> 2) & 3) * 8 + ((tx >> 4) & 1) * 4 + (tx & 3);
    unsigned short* dst = vT + ((size_t)bh * 64 + dt * 32) * 2048 + (size_t)(lt >> 1) * 64;
    #pragma unroll
    for (int r = 0; r < 4; r++)
        dst[(size_t)(ty + r * 8) * 2048 + perm] = tile[tx][ty + r * 8];
}

// ------- GEMM (m97 structure): C[M][N] = A[M][K](bf16) @ Bt[N][K]^T -------
template <int EPI>
__global__ __launch_bounds__(256) void gemm_bt(const unsigned short* __restrict__ A,
                                               const unsigned short* __restrict__ Bt,
                                               const float* __restrict__ bias,
                                               const float* __restrict__ res,
                                               float* __restrict__ outF,
                                               unsigned short* __restrict__ outB,
                                               int M, int N, int K) {
    __shared__ __align__(16) unsigned short As[128 * 32];
    __shared__ __align__(16) unsigned short Bs[128 * 32];
    int t = threadIdx.x;
    int lane = t & 63, wid = t >> 6;

    // XCD-aware bijective swizzle (grid size % 8 == 0 for all our shapes)
    int gx = gridDim.x;
    int nwg = gx * gridDim.y;
    int orig = blockIdx.y * gx + blockIdx.x;
    int cpx = nwg >> 3;
    int swz = (orig & 7) * cpx + (orig >> 3);
    int bm = swz / gx, bn = swz % gx;

    int wm = wid >> 1, wn = wid & 1;
    f32x4 acc[4][4] = {};

    int sub = lane >> 2;        // row within 16
    int chunk = lane & 3;       // 16B chunk within 64B row
    const unsigned short* gA0 = A + (size_t)(bm * 128 + wid * 32 + sub) * K + chunk * 8;
    const unsigned short* gA1 = gA0 + (size_t)16 * K;
    const unsigned short* gB0 = Bt + (size_t)(bn * 128 + wid * 32 + sub) * K + chunk * 8;
    const unsigned short* gB1 = gB0 + (size_t)16 * K;
    unsigned short* lA0 = &As[(wid * 32) * 32];
    unsigned short* lA1 = &As[(wid * 32 + 16) * 32];
    unsigned short* lB0 = &Bs[(wid * 32) * 32];
    unsigned short* lB1 = &Bs[(wid * 32 + 16) * 32];

    for (int k0 = 0; k0 < K; k0 += 32) {
        __syncthreads();
        gload16(gA0 + k0, lA0);
        gload16(gA1 + k0, lA1);
        gload16(gB0 + k0, lB0);
        gload16(gB1 + k0, lB1);
        __syncthreads();
        bf16x8 af[4], bfr[4];
        #pragma unroll
        for (int m = 0; m < 4; m++)
            af[m] = *(const bf16x8*)&As[(wm * 64 + m * 16 + (lane & 15)) * 32 + (lane >> 4) * 8];
        #pragma unroll
        for (int n = 0; n < 4; n++)
            bfr[n] = *(const bf16x8*)&Bs[(wn * 64 + n * 16 + (lane & 15)) * 32 + (lane >> 4) * 8];
        #pragma unroll
        for (int m = 0; m < 4; m++)
            #pragma unroll
            for (int n = 0; n < 4; n++)
                acc[m][n] = mfma16(af[m], bfr[n], acc[m][n]);
    }

    #pragma unroll
    for (int m = 0; m < 4; m++) {
        #pragma unroll
        for (int n = 0; n < 4; n++) {
            int col = bn * 128 + wn * 64 + n * 16 + (lane & 15);
            float bv = bias[col];
            #pragma unroll
            for (int r = 0; r < 4; r++) {
                int row = bm * 128 + wm * 64 + m * 16 + (lane >> 4) * 4 + r;
                float val = acc[m][n][r] + bv;
                if (EPI == 0) {
                    if (col < 1024) val *= QSCALE_LOG2E;  // pre-scale q
                    outB[(size_t)row * N + col] = f2bf(val);
                } else if (EPI == 1) {
                    float g = 0.5f * val *
                              (1.0f + tanhf(0.7978845608028654f *
                                            (val + 0.044715f * val * val * val)));
                    outB[(size_t)row * N + col] = f2bf(g);
                } else {
                    outF[(size_t)row * N + col] = val + res[(size_t)row * N + col];
                }
            }
        }
    }
}

// --- Flash attention v5: swapped QK^T, in-register P, gload_lds staging ---
// K/V tiles stored half-split [c][64][32] so fragment reads are conflict-free
// (chunk = 4*ql + hi, contiguous 1KB per wave-instruction) and staging writes
// are linear (wave base + lane*16) -> global_load_lds eligible.
__global__ __launch_bounds__(256) void attn_kernel(const unsigned short* __restrict__ qkv,
                                                   const unsigned short* __restrict__ vT,
                                                   unsigned short* __restrict__ o) {
    int bid = blockIdx.x;
    int qb = bid & 31;
    int bh = bid >> 5;
    int b = bh >> 4, h = bh & 15;
    int t = threadIdx.x, lane = t & 63, wid = t >> 6;

    const unsigned short* base = qkv + (size_t)b * 2048 * 3072 + h * 64;
    const unsigned short* vbase = vT + (size_t)bh * 64 * 2048;

    __shared__ __align__(16) unsigned short Ks[2][64][32];  // [d-half][key][d']
    __shared__ __align__(16) unsigned short Vs[2][64][32];  // [k-half][d][key']

    int ql = lane & 15;   // q row within wave (also fragment row sub-index)
    int hi = lane >> 4;   // 0..3

    // Q fragments as MFMA B-operand: lane holds Q[q=ql][d=hi*8+j (+32c)]
    bf16x8 qf[2];
    {
        int qrow = qb * 64 + wid * 16 + ql;
        const unsigned short* qp = base + (size_t)qrow * 3072 + hi * 8;
        qf[0] = *(const bf16x8*)(qp);
        qf[1] = *(const bf16x8*)(qp + 32);
    }

    float m_r = -1e30f, lpart = 0.0f;
    f32x4 accO[4] = {};

    // staging: wave w stages rows [16w,16w+16) of each half-tile.
    // lane l covers row 16w + (l>>2), 16B chunk (l&3). LDS dest linear.
    int srow = wid * 16 + (lane >> 2);
    int schunk = (lane & 3) * 8;
    const unsigned short* gk = base + 1024 + (size_t)srow * 3072 + schunk;  // K[key][d]
    const unsigned short* gv = vbase + (size_t)srow * 2048 + schunk;        // V'[d][key']
    unsigned short* lK0 = &Ks[0][wid * 16][0];
    unsigned short* lK1 = &Ks[1][wid * 16][0];
    unsigned short* lV0 = &Vs[0][wid * 16][0];
    unsigned short* lV1 = &Vs[1][wid * 16][0];

    for (int kt = 0; kt < 32; kt++) {
        __syncthreads();
        gload16(gk, lK0);
        gload16(gk + 32, lK1);
        gload16(gv, lV0);
        gload16(gv + 32, lV1);
        gk += (size_t)64 * 3072;
        gv += 64;
        __syncthreads();   // compiler drains vmcnt before barrier

        // swapped QK^T: s_nf = S^T fragment; lane holds q=ql, key nf*16+hi*4+r
        f32x4 s0 = {}, s1 = {}, s2 = {}, s3 = {};
        #pragma unroll
        for (int c = 0; c < 2; c++) {
            bf16x8 a0 = *(const bf16x8*)&Ks[c][ 0 + ql][hi * 8];
            bf16x8 a1 = *(const bf16x8*)&Ks[c][16 + ql][hi * 8];
            bf16x8 a2 = *(const bf16x8*)&Ks[c][32 + ql][hi * 8];
            bf16x8 a3 = *(const bf16x8*)&Ks[c][48 + ql][hi * 8];
            s0 = mfma16(a0, qf[c], s0);
            s1 = mfma16(a1, qf[c], s1);
            s2 = mfma16(a2, qf[c], s2);
            s3 = mfma16(a3, qf[c], s3);
        }

        // defer-max: lane-local 16-value max; slow path only on threshold break
        float mx = fmaxf(fmaxf(fmaxf(s0[0], s0[1]), fmaxf(s0[2], s0[3])),
                         fmaxf(fmaxf(s1[0], s1[1]), fmaxf(s1[2], s1[3])));
        mx = fmaxf(mx, fmaxf(fmaxf(s2[0], s2[1]), fmaxf(s2[2], s2[3])));
        mx = fmaxf(mx, fmaxf(fmaxf(s3[0], s3[1]), fmaxf(s3[2], s3[3])));
        if (!__all(mx <= m_r + 8.0f)) {   // wave-uniform branch
            float mm = fmaxf(mx, __shfl_xor(mx, 16));
            mm = fmaxf(mm, __shfl_xor(mm, 32));
            float mnew = fmaxf(m_r, mm);
            float corr = fast_exp2(m_r - mnew);
            m_r = mnew;
            lpart *= corr;
            #pragma unroll
            for (int r = 0; r < 4; r++) {
                float cq = __shfl(corr, hi * 4 + r);  // corr for q_out=hi*4+r
                accO[0][r] *= cq; accO[1][r] *= cq;
                accO[2][r] *= cq; accO[3][r] *= cq;
            }
        }

        // exp2 -> packed PV A-fragments (in-register, zero cross-lane)
        us8 pu0, pu1;
        #pragma unroll
        for (int j = 0; j < 4; j++) {
            float pa = fast_exp2(s0[j] - m_r);
            float pb = fast_exp2(s1[j] - m_r);
            float pc = fast_exp2(s2[j] - m_r);
            float pd = fast_exp2(s3[j] - m_r);
            lpart += (pa + pb) + (pc + pd);
            pu0[j] = f2bf(pa); pu0[4 + j] = f2bf(pb);
            pu1[j] = f2bf(pc); pu1[4 + j] = f2bf(pd);
        }
        bf16x8 paf0 = __builtin_bit_cast(bf16x8, pu0);
        bf16x8 paf1 = __builtin_bit_cast(bf16x8, pu1);

        // PV: accO[nn] += P[q][key'] * V[key'][d]  (key' = permuted axis)
        #pragma unroll
        for (int nn = 0; nn < 4; nn++) {
            bf16x8 bv0 = *(const bf16x8*)&Vs[0][nn * 16 + ql][hi * 8];
            bf16x8 bv1 = *(const bf16x8*)&Vs[1][nn * 16 + ql][hi * 8];
            accO[nn] = mfma16(paf0, bv0, accO[nn]);
            accO[nn] = mfma16(paf1, bv1, accO[nn]);
        }
    }

    // final: sum per-lane partials across the 4 key-lanes of each q
    lpart += __shfl_xor(lpart, 16);
    lpart += __shfl_xor(lpart, 32);
    float rinv = 1.0f / lpart;
    #pragma unroll
    for (int r = 0; r < 4; r++) {
        float rq = __shfl(rinv, hi * 4 + r);
        int row = qb * 64 + wid * 16 + hi * 4 + r;
        #pragma unroll
        for (int nn = 0; nn < 4; nn++) {
            int col = h * 64 + nn * 16 + ql;
            o[(size_t)(b * 2048 + row) * 1024 + col] = f2bf(accO[nn][r] * rq);
        }
    }
}

extern "C" void kernel_launch(void* const* d_in, const int* in_sizes, int n_in,
                              void* d_out, int out_size, void* d_ws, size_t ws_size,
                              hipStream_t stream) {
    const float* x      = (const float*)d_in[0];
    const float* qkv_w  = (const float*)d_in[1];
    const float* qkv_b  = (const float*)d_in[2];
    const float* proj_w = (const float*)d_in[3];
    const float* proj_b = (const float*)d_in[4];
    const float* fc1_w  = (const float*)d_in[5];
    const float* fc1_b  = (const float*)d_in[6];
    const float* fc2_w  = (const float*)d_in[7];
    const float* fc2_b  = (const float*)d_in[8];
    float* out = (float*)d_out;

    char* ws = (char*)d_ws;
    unsigned short* h_buf   = (unsigned short*)(ws + 0 * MBYTE);    // 16 MB (reused for h2)
    unsigned short* qkv_buf = (unsigned short*)(ws + 16 * MBYTE);   // 48 MB
    unsigned short* o_buf   = (unsigned short*)(ws + 64 * MBYTE);   // 16 MB
    float*          x2_buf  = (float*)(ws + 80 * MBYTE);            // 32 MB
    unsigned short* vT_buf  = (unsigned short*)(ws + 80 * MBYTE);   // 17 MB (dead before x2 written)
    unsigned short* wqT     = (unsigned short*)(ws + 112 * MBYTE);  // 6 MB
    unsigned short* wpT     = (unsigned short*)(ws + 118 * MBYTE);  // 2 MB
    unsigned short* w1T     = (unsigned short*)(ws + 120 * MBYTE);  // 8 MB
    unsigned short* w2T     = (unsigned short*)(ws + 128 * MBYTE);  // 8 MB
    unsigned short* g_buf   = (unsigned short*)(ws + 16 * MBYTE);   // 64 MB (reuse qkv+o)

    const int M = 8192;  // B*L

    convT_kernel<<<dim3(3072 / 32, 1024 / 32), 256, 0, stream>>>(qkv_w, wqT, 1024, 3072);
    convT_kernel<<<dim3(1024 / 32, 1024 / 32), 256, 0, stream>>>(proj_w, wpT, 1024, 1024);
    convT_kernel<<<dim3(4096 / 32, 1024 / 32), 256, 0, stream>>>(fc1_w, w1T, 1024, 4096);
    convT_kernel<<<dim3(1024 / 32, 4096 / 32), 256, 0, stream>>>(fc2_w, w2T, 4096, 1024);

    ln_kernel<<<M, 256, 0, stream>>>(x, h_buf);

    gemm_bt<0><<<dim3(3072 / 128, M / 128), 256, 0, stream>>>(
        h_buf, wqT, qkv_b, nullptr, nullptr, qkv_buf, M, 3072, 1024);

    vT_kernel<<<dim3(64, 2, 64), 256, 0, stream>>>(qkv_buf, vT_buf);

    attn_kernel<<<dim3(32 * 64), 256, 0, stream>>>(qkv_buf, vT_buf, o_buf);

    gemm_bt<2><<<dim3(1024 / 128, M / 128), 256, 0, stream>>>(
        o_buf, wpT, proj_b, x, x2_buf, nullptr, M, 1024, 1024);

    ln_kernel<<<M, 256, 0, stream>>>(x2_buf, h_buf);

    gemm_bt<1><<<dim3(4096 / 128, M / 128), 256, 0, stream>>>(
        h_buf, w1T, fc1_b, nullptr, nullptr, g_buf, M, 4096, 1024);

    gemm_bt<2><<<dim3(1024 / 128, M / 128), 256, 0, stream>>>(
        g_buf, w2T, fc2_b, x2_buf, out, nullptr, M, 1024, 4096);
}

// Round 7
// 448.993 us; speedup vs baseline: 1.7916x; 1.0521x over previous
//
#include <hip/hip_runtime.h>
#include <hip/hip_bf16.h>

typedef float f32x4 __attribute__((ext_vector_type(4)));
typedef __bf16 bf16x8 __attribute__((ext_vector_type(8)));
typedef unsigned short us8 __attribute__((ext_vector_type(8)));

#define MBYTE (1ull << 20)

// scale * log2(e): Q pre-scaled so attention logits are in log2 domain
#define QSCALE_LOG2E 0.18033688011112042f
// 2 * 0.7978845608 * log2(e) for sigmoid-form gelu
#define GELU_K 2.3022081902f

__device__ __forceinline__ unsigned short f2bf(float f) {
    __bf16 h = (__bf16)f;   // native cvt (RTNE)
    return __builtin_bit_cast(unsigned short, h);
}

__device__ __forceinline__ float fast_exp2(float x) {
    return __builtin_amdgcn_exp2f(x);
}

__device__ __forceinline__ f32x4 mfma16(bf16x8 a, bf16x8 b, f32x4 c) {
    return __builtin_amdgcn_mfma_f32_16x16x32_bf16(a, b, c, 0, 0, 0);
}

// async global->LDS, 16B per lane, dest = wave-uniform base + lane*16
__device__ __forceinline__ void gload16(const void* g, void* l) {
    __builtin_amdgcn_global_load_lds(
        (const __attribute__((address_space(1))) unsigned int*)g,
        (__attribute__((address_space(3))) unsigned int*)l, 16, 0, 0);
}

// ---------------- LayerNorm: fp32 [rows][1024] -> bf16 ----------------
__global__ __launch_bounds__(256) void ln_kernel(const float* __restrict__ x,
                                                 unsigned short* __restrict__ out) {
    int row = blockIdx.x;
    int t = threadIdx.x;
    const float* xr = x + (size_t)row * 1024;
    float4 v = *(const float4*)(xr + t * 4);
    float s = v.x + v.y + v.z + v.w;
    float ss = v.x * v.x + v.y * v.y + v.z * v.z + v.w * v.w;
    #pragma unroll
    for (int off = 1; off < 64; off <<= 1) {
        s += __shfl_xor(s, off);
        ss += __shfl_xor(ss, off);
    }
    __shared__ float ps[4], pss[4];
    int wid = t >> 6, lane = t & 63;
    if (lane == 0) { ps[wid] = s; pss[wid] = ss; }
    __syncthreads();
    s = ps[0] + ps[1] + ps[2] + ps[3];
    ss = pss[0] + pss[1] + pss[2] + pss[3];
    float mean = s * (1.0f / 1024.0f);
    float var = ss * (1.0f / 1024.0f) - mean * mean;
    float rs = rsqrtf(var + 1e-6f);
    ushort4 ov;
    ov.x = f2bf((v.x - mean) * rs);
    ov.y = f2bf((v.y - mean) * rs);
    ov.z = f2bf((v.z - mean) * rs);
    ov.w = f2bf((v.w - mean) * rs);
    *(ushort4*)(out + (size_t)row * 1024 + t * 4) = ov;
}

// ------------- transpose + fp32->bf16: W[K][N] -> Wt[N][K] -------------
__global__ __launch_bounds__(256) void convT_kernel(const float* __restrict__ W,
                                                    unsigned short* __restrict__ Wt,
                                                    int K, int N) {
    __shared__ float tile[32][33];
    int t = threadIdx.x;
    int tx = t & 31, ty = t >> 5;  // ty 0..7
    int bx = blockIdx.x, by = blockIdx.y;
    #pragma unroll
    for (int r = 0; r < 4; r++) {
        int row = by * 32 + ty + r * 8;
        int col = bx * 32 + tx;
        tile[ty + r * 8][tx] = W[(size_t)row * N + col];
    }
    __syncthreads();
    #pragma unroll
    for (int r = 0; r < 4; r++) {
        int orow = bx * 32 + ty + r * 8;  // n
        int ocol = by * 32 + tx;          // k
        Wt[(size_t)orow * K + ocol] = f2bf(tile[tx][ty + r * 8]);
    }
}

// ------------- V transpose: qkv V-part bf16 -> vT[bh][64][2048] -------------
// Key axis is PERMUTED within each 64-key tile so that the attention kernel's
// in-register P fragments line up with V columns:
//   orig key (nf,hi,r) = nf*16 + hi*4 + r  ->  (nf>>1)*32 + hi*8 + (nf&1)*4 + r
__global__ __launch_bounds__(256) void vT_kernel(const unsigned short* __restrict__ qkv,
                                                 unsigned short* __restrict__ vT) {
    __shared__ unsigned short tile[32][34];
    int t = threadIdx.x;
    int tx = t & 31, ty = t >> 5;  // ty 0..7
    int lt = blockIdx.x, dt = blockIdx.y, bh = blockIdx.z;
    int b = bh >> 4, h = bh & 15;
    const unsigned short* src = qkv + (size_t)(b * 2048 + lt * 32) * 3072 + 2048 + h * 64 + dt * 32;
    #pragma unroll
    for (int r = 0; r < 4; r++)
        tile[ty + r * 8][tx] = src[(size_t)(ty + r * 8) * 3072 + tx];
    __syncthreads();
    // permuted column within the 64-key tile
    int perm = (lt & 1) * 32 + ((tx >> 2) & 3) * 8 + ((tx >> 4) & 1) * 4 + (tx & 3);
    unsigned short* dst = vT + ((size_t)bh * 64 + dt * 32) * 2048 + (size_t)(lt >> 1) * 64;
    #pragma unroll
    for (int r = 0; r < 4; r++)
        dst[(size_t)(ty + r * 8) * 2048 + perm] = tile[tx][ty + r * 8];
}

// ------- GEMM v2: double-buffered LDS + both-sides XOR swizzle -------
// C[M][N] = A[M][K](bf16) @ Bt[N][K]^T. gload_lds staging (linear dest,
// pre-swizzled source chunk), conflict-free ds_read_b128 fragments,
// one barrier per K-step; next tile's loads fly under current MFMA.
template <int EPI>
__global__ __launch_bounds__(256) void gemm_bt(const unsigned short* __restrict__ A,
                                               const unsigned short* __restrict__ Bt,
                                               const float* __restrict__ bias,
                                               const float* __restrict__ res,
                                               float* __restrict__ outF,
                                               unsigned short* __restrict__ outB,
                                               int M, int N, int K) {
    __shared__ __align__(16) unsigned short As[2][128 * 32];
    __shared__ __align__(16) unsigned short Bs[2][128 * 32];
    int t = threadIdx.x;
    int lane = t & 63, wid = t >> 6;

    // XCD-aware bijective swizzle (grid size % 8 == 0 for all our shapes)
    int gx = gridDim.x;
    int nwg = gx * gridDim.y;
    int orig = blockIdx.y * gx + blockIdx.x;
    int cpx = nwg >> 3;
    int swz = (orig & 7) * cpx + (orig >> 3);
    int bm = swz / gx, bn = swz % gx;

    int wm = wid >> 1, wn = wid & 1;
    f32x4 acc[4][4] = {};

    // staging: wave w covers LDS rows [w*32, w*32+32) in two 16-row calls.
    // LDS slot (row, c) holds global chunk (c ^ ((row>>1)&3))  [rule #21:
    // linear dest + inverse-swizzled source + same XOR on read]
    int sub = lane >> 2;                                   // row within 16
    int schunk = ((lane & 3) ^ ((lane >> 3) & 3)) * 8;     // swizzled src chunk
    const unsigned short* gA0 = A + (size_t)(bm * 128 + wid * 32 + sub) * K + schunk;
    const unsigned short* gA1 = gA0 + (size_t)16 * K;
    const unsigned short* gB0 = Bt + (size_t)(bn * 128 + wid * 32 + sub) * K + schunk;
    const unsigned short* gB1 = gB0 + (size_t)16 * K;

    // fragment-read chunk: global chunk hi lives at slot hi ^ ((ql>>1)&3)
    int ql = lane & 15;
    int rchunk = (((lane >> 4) ^ ((lane >> 1) & 3))) * 8;

    const int NT = K >> 5;
    // prologue: stage tile 0 into buffer 0
    gload16(gA0, &As[0][(wid * 32) * 32]);
    gload16(gA1, &As[0][(wid * 32 + 16) * 32]);
    gload16(gB0, &Bs[0][(wid * 32) * 32]);
    gload16(gB1, &Bs[0][(wid * 32 + 16) * 32]);
    __syncthreads();   // drains vmcnt

    int cur = 0;
    for (int tt = 0; tt < NT; ++tt) {
        if (tt + 1 < NT) {     // issue next tile's loads into other buffer
            int k0 = (tt + 1) << 5;
            int nb = cur ^ 1;
            gload16(gA0 + k0, &As[nb][(wid * 32) * 32]);
            gload16(gA1 + k0, &As[nb][(wid * 32 + 16) * 32]);
            gload16(gB0 + k0, &Bs[nb][(wid * 32) * 32]);
            gload16(gB1 + k0, &Bs[nb][(wid * 32 + 16) * 32]);
        }
        bf16x8 af[4], bfr[4];
        #pragma unroll
        for (int m = 0; m < 4; m++)
            af[m] = *(const bf16x8*)&As[cur][(wm * 64 + m * 16 + ql) * 32 + rchunk];
        #pragma unroll
        for (int n = 0; n < 4; n++)
            bfr[n] = *(const bf16x8*)&Bs[cur][(wn * 64 + n * 16 + ql) * 32 + rchunk];
        __builtin_amdgcn_s_setprio(1);
        #pragma unroll
        for (int m = 0; m < 4; m++)
            #pragma unroll
            for (int n = 0; n < 4; n++)
                acc[m][n] = mfma16(af[m], bfr[n], acc[m][n]);
        __builtin_amdgcn_s_setprio(0);
        __syncthreads();   // drains next-tile loads (covered by MFMA above)
        cur ^= 1;
    }

    #pragma unroll
    for (int m = 0; m < 4; m++) {
        #pragma unroll
        for (int n = 0; n < 4; n++) {
            int col = bn * 128 + wn * 64 + n * 16 + ql;
            float bv = bias[col];
            #pragma unroll
            for (int r = 0; r < 4; r++) {
                int row = bm * 128 + wm * 64 + m * 16 + (lane >> 4) * 4 + r;
                float val = acc[m][n][r] + bv;
                if (EPI == 0) {
                    if (col < 1024) val *= QSCALE_LOG2E;  // pre-scale q
                    outB[(size_t)row * N + col] = f2bf(val);
                } else if (EPI == 1) {
                    // gelu_tanh == v * sigmoid(2*0.79788456*(v+0.044715 v^3))
                    float w = val + 0.044715f * val * val * val;
                    float g = val / (1.0f + fast_exp2(-GELU_K * w));
                    outB[(size_t)row * N + col] = f2bf(g);
                } else {
                    outF[(size_t)row * N + col] = val + res[(size_t)row * N + col];
                }
            }
        }
    }
}

// --- Flash attention v5: swapped QK^T, in-register P, gload_lds staging ---
__global__ __launch_bounds__(256) void attn_kernel(const unsigned short* __restrict__ qkv,
                                                   const unsigned short* __restrict__ vT,
                                                   unsigned short* __restrict__ o) {
    int bid = blockIdx.x;
    int qb = bid & 31;
    int bh = bid >> 5;
    int b = bh >> 4, h = bh & 15;
    int t = threadIdx.x, lane = t & 63, wid = t >> 6;

    const unsigned short* base = qkv + (size_t)b * 2048 * 3072 + h * 64;
    const unsigned short* vbase = vT + (size_t)bh * 64 * 2048;

    __shared__ __align__(16) unsigned short Ks[2][64][32];  // [d-half][key][d']
    __shared__ __align__(16) unsigned short Vs[2][64][32];  // [k-half][d][key']

    int ql = lane & 15;
    int hi = lane >> 4;

    bf16x8 qf[2];
    {
        int qrow = qb * 64 + wid * 16 + ql;
        const unsigned short* qp = base + (size_t)qrow * 3072 + hi * 8;
        qf[0] = *(const bf16x8*)(qp);
        qf[1] = *(const bf16x8*)(qp + 32);
    }

    float m_r = -1e30f, lpart = 0.0f;
    f32x4 accO[4] = {};

    int srow = wid * 16 + (lane >> 2);
    int schunk = (lane & 3) * 8;
    const unsigned short* gk = base + 1024 + (size_t)srow * 3072 + schunk;
    const unsigned short* gv = vbase + (size_t)srow * 2048 + schunk;
    unsigned short* lK0 = &Ks[0][wid * 16][0];
    unsigned short* lK1 = &Ks[1][wid * 16][0];
    unsigned short* lV0 = &Vs[0][wid * 16][0];
    unsigned short* lV1 = &Vs[1][wid * 16][0];

    for (int kt = 0; kt < 32; kt++) {
        __syncthreads();
        gload16(gk, lK0);
        gload16(gk + 32, lK1);
        gload16(gv, lV0);
        gload16(gv + 32, lV1);
        gk += (size_t)64 * 3072;
        gv += 64;
        __syncthreads();

        f32x4 s0 = {}, s1 = {}, s2 = {}, s3 = {};
        #pragma unroll
        for (int c = 0; c < 2; c++) {
            bf16x8 a0 = *(const bf16x8*)&Ks[c][ 0 + ql][hi * 8];
            bf16x8 a1 = *(const bf16x8*)&Ks[c][16 + ql][hi * 8];
            bf16x8 a2 = *(const bf16x8*)&Ks[c][32 + ql][hi * 8];
            bf16x8 a3 = *(const bf16x8*)&Ks[c][48 + ql][hi * 8];
            s0 = mfma16(a0, qf[c], s0);
            s1 = mfma16(a1, qf[c], s1);
            s2 = mfma16(a2, qf[c], s2);
            s3 = mfma16(a3, qf[c], s3);
        }

        float mx = fmaxf(fmaxf(fmaxf(s0[0], s0[1]), fmaxf(s0[2], s0[3])),
                         fmaxf(fmaxf(s1[0], s1[1]), fmaxf(s1[2], s1[3])));
        mx = fmaxf(mx, fmaxf(fmaxf(s2[0], s2[1]), fmaxf(s2[2], s2[3])));
        mx = fmaxf(mx, fmaxf(fmaxf(s3[0], s3[1]), fmaxf(s3[2], s3[3])));
        if (!__all(mx <= m_r + 8.0f)) {
            float mm = fmaxf(mx, __shfl_xor(mx, 16));
            mm = fmaxf(mm, __shfl_xor(mm, 32));
            float mnew = fmaxf(m_r, mm);
            float corr = fast_exp2(m_r - mnew);
            m_r = mnew;
            lpart *= corr;
            #pragma unroll
            for (int r = 0; r < 4; r++) {
                float cq = __shfl(corr, hi * 4 + r);
                accO[0][r] *= cq; accO[1][r] *= cq;
                accO[2][r] *= cq; accO[3][r] *= cq;
            }
        }

        us8 pu0, pu1;
        #pragma unroll
        for (int j = 0; j < 4; j++) {
            float pa = fast_exp2(s0[j] - m_r);
            float pb = fast_exp2(s1[j] - m_r);
            float pc = fast_exp2(s2[j] - m_r);
            float pd = fast_exp2(s3[j] - m_r);
            lpart += (pa + pb) + (pc + pd);
            pu0[j] = f2bf(pa); pu0[4 + j] = f2bf(pb);
            pu1[j] = f2bf(pc); pu1[4 + j] = f2bf(pd);
        }
        bf16x8 paf0 = __builtin_bit_cast(bf16x8, pu0);
        bf16x8 paf1 = __builtin_bit_cast(bf16x8, pu1);

        #pragma unroll
        for (int nn = 0; nn < 4; nn++) {
            bf16x8 bv0 = *(const bf16x8*)&Vs[0][nn * 16 + ql][hi * 8];
            bf16x8 bv1 = *(const bf16x8*)&Vs[1][nn * 16 + ql][hi * 8];
            accO[nn] = mfma16(paf0, bv0, accO[nn]);
            accO[nn] = mfma16(paf1, bv1, accO[nn]);
        }
    }

    lpart += __shfl_xor(lpart, 16);
    lpart += __shfl_xor(lpart, 32);
    float rinv = 1.0f / lpart;
    #pragma unroll
    for (int r = 0; r < 4; r++) {
        float rq = __shfl(rinv, hi * 4 + r);
        int row = qb * 64 + wid * 16 + hi * 4 + r;
        #pragma unroll
        for (int nn = 0; nn < 4; nn++) {
            int col = h * 64 + nn * 16 + ql;
            o[(size_t)(b * 2048 + row) * 1024 + col] = f2bf(accO[nn][r] * rq);
        }
    }
}

extern "C" void kernel_launch(void* const* d_in, const int* in_sizes, int n_in,
                              void* d_out, int out_size, void* d_ws, size_t ws_size,
                              hipStream_t stream) {
    const float* x      = (const float*)d_in[0];
    const float* qkv_w  = (const float*)d_in[1];
    const float* qkv_b  = (const float*)d_in[2];
    const float* proj_w = (const float*)d_in[3];
    const float* proj_b = (const float*)d_in[4];
    const float* fc1_w  = (const float*)d_in[5];
    const float* fc1_b  = (const float*)d_in[6];
    const float* fc2_w  = (const float*)d_in[7];
    const float* fc2_b  = (const float*)d_in[8];
    float* out = (float*)d_out;

    char* ws = (char*)d_ws;
    unsigned short* h_buf   = (unsigned short*)(ws + 0 * MBYTE);    // 16 MB (reused for h2)
    unsigned short* qkv_buf = (unsigned short*)(ws + 16 * MBYTE);   // 48 MB
    unsigned short* o_buf   = (unsigned short*)(ws + 64 * MBYTE);   // 16 MB
    float*          x2_buf  = (float*)(ws + 80 * MBYTE);            // 32 MB
    unsigned short* vT_buf  = (unsigned short*)(ws + 80 * MBYTE);   // 17 MB (dead before x2 written)
    unsigned short* wqT     = (unsigned short*)(ws + 112 * MBYTE);  // 6 MB
    unsigned short* wpT     = (unsigned short*)(ws + 118 * MBYTE);  // 2 MB
    unsigned short* w1T     = (unsigned short*)(ws + 120 * MBYTE);  // 8 MB
    unsigned short* w2T     = (unsigned short*)(ws + 128 * MBYTE);  // 8 MB
    unsigned short* g_buf   = (unsigned short*)(ws + 16 * MBYTE);   // 64 MB (reuse qkv+o)

    const int M = 8192;  // B*L

    convT_kernel<<<dim3(3072 / 32, 1024 / 32), 256, 0, stream>>>(qkv_w, wqT, 1024, 3072);
    convT_kernel<<<dim3(1024 / 32, 1024 / 32), 256, 0, stream>>>(proj_w, wpT, 1024, 1024);
    convT_kernel<<<dim3(4096 / 32, 1024 / 32), 256, 0, stream>>>(fc1_w, w1T, 1024, 4096);
    convT_kernel<<<dim3(1024 / 32, 4096 / 32), 256, 0, stream>>>(fc2_w, w2T, 4096, 1024);

    ln_kernel<<<M, 256, 0, stream>>>(x, h_buf);

    gemm_bt<0><<<dim3(3072 / 128, M / 128), 256, 0, stream>>>(
        h_buf, wqT, qkv_b, nullptr, nullptr, qkv_buf, M, 3072, 1024);

    vT_kernel<<<dim3(64, 2, 64), 256, 0, stream>>>(qkv_buf, vT_buf);

    attn_kernel<<<dim3(32 * 64), 256, 0, stream>>>(qkv_buf, vT_buf, o_buf);

    gemm_bt<2><<<dim3(1024 / 128, M / 128), 256, 0, stream>>>(
        o_buf, wpT, proj_b, x, x2_buf, nullptr, M, 1024, 1024);

    ln_kernel<<<M, 256, 0, stream>>>(x2_buf, h_buf);

    gemm_bt<1><<<dim3(4096 / 128, M / 128), 256, 0, stream>>>(
        h_buf, w1T, fc1_b, nullptr, nullptr, g_buf, M, 4096, 1024);

    gemm_bt<2><<<dim3(1024 / 128, M / 128), 256, 0, stream>>>(
        g_buf, w2T, fc2_b, x2_buf, out, nullptr, M, 1024, 4096);
}